// Round 2
// baseline (438.367 us; speedup 1.0000x reference)
//
#include <hip/hip_runtime.h>
#include <math.h>

__device__ __forceinline__ float lrelu(float v) { return v > 0.0f ? v : 0.2f * v; }

// ---- Kernel A: fold attention vectors into W: wsrc[k,h] = sum_c W[k,h*64+c]*att_src[h,c]
__global__ void patt_kernel(const float* __restrict__ W, const float* __restrict__ att_src,
                            const float* __restrict__ att_dst, float* __restrict__ wsrc,
                            float* __restrict__ wdst) {
  int t = threadIdx.x;            // 256 threads: h = t>>6, k = t&63
  int h = t >> 6, k = t & 63;
  const float* wrow = W + (size_t)k * 256 + h * 64;
  const float* as = att_src + h * 64;
  const float* ad = att_dst + h * 64;
  float ss = 0.f, sd = 0.f;
#pragma unroll
  for (int c = 0; c < 64; ++c) {
    float w = wrow[c];
    ss = fmaf(w, as[c], ss);
    sd = fmaf(w, ad[c], sd);
  }
  wsrc[k * 4 + h] = ss;
  wdst[k * 4 + h] = sd;
}

// ---- Kernel B: per-node attention scalars a_src/a_dst = meta_x @ wsrc/wdst  -> [N,4]
__global__ void nattn_kernel(const float* __restrict__ x, const float4* __restrict__ wsrc4,
                             const float4* __restrict__ wdst4, float4* __restrict__ asrc4,
                             float4* __restrict__ adst4, int N) {
  int lane = threadIdx.x & 63;
  int n = blockIdx.x * 4 + (threadIdx.x >> 6);
  if (n >= N) return;
  float xv = x[(size_t)n * 64 + lane];
  float4 ws = wsrc4[lane], wd = wdst4[lane];
  float s0 = xv * ws.x, s1 = xv * ws.y, s2 = xv * ws.z, s3 = xv * ws.w;
  float d0 = xv * wd.x, d1 = xv * wd.y, d2 = xv * wd.z, d3 = xv * wd.w;
#pragma unroll
  for (int m = 1; m < 64; m <<= 1) {
    s0 += __shfl_xor(s0, m, 64); s1 += __shfl_xor(s1, m, 64);
    s2 += __shfl_xor(s2, m, 64); s3 += __shfl_xor(s3, m, 64);
    d0 += __shfl_xor(d0, m, 64); d1 += __shfl_xor(d1, m, 64);
    d2 += __shfl_xor(d2, m, 64); d3 += __shfl_xor(d3, m, 64);
  }
  if (lane == 0) {
    asrc4[n] = make_float4(s0, s1, s2, s3);
    adst4[n] = make_float4(d0, d1, d2, d3);
  }
}

// ---- Kernel C: histogram of destinations (self-loops appended at the end)
__global__ void hist_kernel(const int* __restrict__ ei, int* __restrict__ counts,
                            int E, int N) {
  int e = blockIdx.x * 256 + threadIdx.x;
  int ET = E + N;
  if (e >= ET) return;
  int dst = (e < E) ? ei[(size_t)E + e] : (e - E);
  atomicAdd(&counts[dst], 1);
}

// ---- Kernel D: single-block exclusive scan -> row_start[N+1], cursor copy
__global__ void scan_kernel(const int* __restrict__ counts, int* __restrict__ row_start,
                            int* __restrict__ cursor, int N) {
  __shared__ int part[1024];
  int t = threadIdx.x;
  int chunk = (N + 1023) >> 10;
  int base = t * chunk;
  int s = 0;
  for (int i = 0; i < chunk; ++i) {
    int idx = base + i;
    if (idx < N) s += counts[idx];
  }
  part[t] = s;
  __syncthreads();
  for (int d = 1; d < 1024; d <<= 1) {
    int v = (t >= d) ? part[t - d] : 0;
    __syncthreads();
    part[t] += v;
    __syncthreads();
  }
  int run = (t == 0) ? 0 : part[t - 1];
  for (int i = 0; i < chunk; ++i) {
    int idx = base + i;
    if (idx < N) {
      row_start[idx] = run;
      cursor[idx] = run;
      run += counts[idx];
      if (idx == N - 1) row_start[N] = run;
    }
  }
}

// ---- Kernel E: scatter edge sources into dst-sorted order
__global__ void scatter_kernel(const int* __restrict__ ei, int* __restrict__ cursor,
                               int* __restrict__ src_sorted, int E, int N) {
  int e = blockIdx.x * 256 + threadIdx.x;
  int ET = E + N;
  if (e >= ET) return;
  int src, dst;
  if (e < E) {
    src = ei[e];
    dst = ei[(size_t)E + e];
  } else {
    src = dst = e - E;
  }
  int pos = atomicAdd(&cursor[dst], 1);
  src_sorted[pos] = src;
}

// ---- Kernel F (fused): per-node softmax + weighted aggregation + output projection.
// Block = 4 waves = 4 nodes. Phase 1: wave w handles node n0+w (softmax over its
// in-edges, alpha-weighted sum of meta_x rows -> aggL[node][head][k], mean folded).
// Phase 2: wave w = head h: project aggL through W (held in 64 VGPRs/lane),
// partials in pL, then wave w = node w sums heads, adds bias, stores out.
__global__ __launch_bounds__(256) void gatout_kernel(
    const int* __restrict__ src_sorted, const int* __restrict__ row_start,
    const float4* __restrict__ asrc4, const float4* __restrict__ adst4,
    const float* __restrict__ x, const float* __restrict__ W,
    const float* __restrict__ bias, float* __restrict__ out, int N) {
  __shared__ float aggL[4][4][64];   // [node_in_block][head][k]
  __shared__ float pL[4][4][64];     // [head][node_in_block][c]
  int t = threadIdx.x;
  int w = t >> 6, lane = t & 63;
  float Wreg[64];                    // W[k, w*64 + lane], k = 0..63
#pragma unroll
  for (int k = 0; k < 64; ++k) Wreg[k] = W[(size_t)k * 256 + w * 64 + lane];
  float bv = bias[lane];
  int ngroups = (N + 3) >> 2;
  for (int g = blockIdx.x; g < ngroups; g += gridDim.x) {
    int n = g * 4 + w;
    float a0 = 0.f, a1 = 0.f, a2 = 0.f, a3 = 0.f;
    if (n < N) {
      int start = row_start[n], end = row_start[n + 1];
      float4 ad = adst4[n];
      // Pass A: per-lane online softmax (max m, sum t) over this node's edges
      float m0 = -1e30f, m1 = -1e30f, m2 = -1e30f, m3 = -1e30f;
      float t0 = 0.f, t1 = 0.f, t2 = 0.f, t3 = 0.f;
      for (int e = start + lane; e < end; e += 64) {
        int s = src_sorted[e];
        float4 as = asrc4[s];
        float l0 = lrelu(as.x + ad.x), l1 = lrelu(as.y + ad.y);
        float l2 = lrelu(as.z + ad.z), l3 = lrelu(as.w + ad.w);
        float nm;
        nm = fmaxf(m0, l0); t0 = t0 * expf(m0 - nm) + expf(l0 - nm); m0 = nm;
        nm = fmaxf(m1, l1); t1 = t1 * expf(m1 - nm) + expf(l1 - nm); m1 = nm;
        nm = fmaxf(m2, l2); t2 = t2 * expf(m2 - nm) + expf(l2 - nm); m2 = nm;
        nm = fmaxf(m3, l3); t3 = t3 * expf(m3 - nm) + expf(l3 - nm); m3 = nm;
      }
      // butterfly merge across 64 lanes
#pragma unroll
      for (int msk = 1; msk < 64; msk <<= 1) {
        float om, os, nm;
        om = __shfl_xor(m0, msk, 64); os = __shfl_xor(t0, msk, 64);
        nm = fmaxf(m0, om); t0 = t0 * expf(m0 - nm) + os * expf(om - nm); m0 = nm;
        om = __shfl_xor(m1, msk, 64); os = __shfl_xor(t1, msk, 64);
        nm = fmaxf(m1, om); t1 = t1 * expf(m1 - nm) + os * expf(om - nm); m1 = nm;
        om = __shfl_xor(m2, msk, 64); os = __shfl_xor(t2, msk, 64);
        nm = fmaxf(m2, om); t2 = t2 * expf(m2 - nm) + os * expf(om - nm); m2 = nm;
        om = __shfl_xor(m3, msk, 64); os = __shfl_xor(t3, msk, 64);
        nm = fmaxf(m3, om); t3 = t3 * expf(m3 - nm) + os * expf(om - nm); m3 = nm;
      }
      float r0 = 1.f / (t0 + 1e-16f), r1 = 1.f / (t1 + 1e-16f);
      float r2 = 1.f / (t2 + 1e-16f), r3 = 1.f / (t3 + 1e-16f);
      // Pass B: lane = channel k; loop edges, alpha broadcast via shuffles
      for (int base = start; base < end; base += 64) {
        int cnt = end - base;
        if (cnt > 64) cnt = 64;
        int idx = base + lane;
        int sl = 0;
        float e0 = 0.f, e1 = 0.f, e2 = 0.f, e3 = 0.f;
        if (idx < end) {
          sl = src_sorted[idx];
          float4 as = asrc4[sl];
          e0 = expf(lrelu(as.x + ad.x) - m0) * r0;
          e1 = expf(lrelu(as.y + ad.y) - m1) * r1;
          e2 = expf(lrelu(as.z + ad.z) - m2) * r2;
          e3 = expf(lrelu(as.w + ad.w) - m3) * r3;
        }
        for (int j = 0; j < cnt; ++j) {
          int sj = __shfl(sl, j, 64);
          float b0 = __shfl(e0, j, 64), b1 = __shfl(e1, j, 64);
          float b2 = __shfl(e2, j, 64), b3 = __shfl(e3, j, 64);
          float v = x[(size_t)sj * 64 + lane];
          a0 = fmaf(b0, v, a0);
          a1 = fmaf(b1, v, a1);
          a2 = fmaf(b2, v, a2);
          a3 = fmaf(b3, v, a3);
        }
      }
    }
    __syncthreads();               // previous iteration's phase 2 done with aggL
    aggL[w][0][lane] = a0 * 0.25f; // fold mean over heads
    aggL[w][1][lane] = a1 * 0.25f;
    aggL[w][2][lane] = a2 * 0.25f;
    aggL[w][3][lane] = a3 * 0.25f;
    __syncthreads();
    // Phase 2: wave w = head w. pL[w][i][c] = sum_k aggL[i][w][k] * W[k, w*64+c]
#pragma unroll
    for (int i = 0; i < 4; ++i) {
      float acc = 0.f;
#pragma unroll
      for (int k = 0; k < 64; ++k) acc = fmaf(aggL[i][w][k], Wreg[k], acc);
      pL[w][i][lane] = acc;
    }
    __syncthreads();
    if (n < N) {
      out[(size_t)n * 64 + lane] = pL[0][w][lane] + pL[1][w][lane] +
                                   pL[2][w][lane] + pL[3][w][lane] + bv;
    }
  }
}

extern "C" void kernel_launch(void* const* d_in, const int* in_sizes, int n_in,
                              void* d_out, int out_size, void* d_ws, size_t ws_size,
                              hipStream_t stream) {
  const float* meta_x = (const float*)d_in[0];
  const int* ei = (const int*)d_in[1];     // harness delivers integer inputs as int32
  const float* W = (const float*)d_in[2];
  const float* att_src = (const float*)d_in[3];
  const float* att_dst = (const float*)d_in[4];
  const float* bias = (const float*)d_in[5];
  float* out = (float*)d_out;

  int N = in_sizes[0] / 64;
  int E = in_sizes[1] / 2;
  int ET = E + N;

  char* ws = (char*)d_ws;
  size_t off = 0;
  auto alloc = [&](size_t bytes) {
    size_t o = off;
    off += (bytes + 255) & ~(size_t)255;
    return o;
  };
  size_t o_wsrc = alloc(64 * 4 * sizeof(float));
  size_t o_wdst = alloc(64 * 4 * sizeof(float));
  size_t o_asrc = alloc((size_t)N * 4 * sizeof(float));
  size_t o_adst = alloc((size_t)N * 4 * sizeof(float));
  size_t o_cnt = alloc((size_t)N * sizeof(int));
  size_t o_row = alloc(((size_t)N + 1) * sizeof(int));
  size_t o_cur = alloc((size_t)N * sizeof(int));
  size_t o_srt = alloc((size_t)ET * sizeof(int));
  (void)ws_size;   // total ~5.6 MB

  float* wsrc = (float*)(ws + o_wsrc);
  float* wdst = (float*)(ws + o_wdst);
  float4* asrc4 = (float4*)(ws + o_asrc);
  float4* adst4 = (float4*)(ws + o_adst);
  int* cnt = (int*)(ws + o_cnt);
  int* row = (int*)(ws + o_row);
  int* cur = (int*)(ws + o_cur);
  int* srt = (int*)(ws + o_srt);

  hipMemsetAsync(cnt, 0, (size_t)N * sizeof(int), stream);

  patt_kernel<<<1, 256, 0, stream>>>(W, att_src, att_dst, wsrc, wdst);
  nattn_kernel<<<(N + 3) / 4, 256, 0, stream>>>(meta_x, (const float4*)wsrc,
                                                (const float4*)wdst, asrc4, adst4, N);
  hist_kernel<<<(ET + 255) / 256, 256, 0, stream>>>(ei, cnt, E, N);
  scan_kernel<<<1, 1024, 0, stream>>>(cnt, row, cur, N);
  scatter_kernel<<<(ET + 255) / 256, 256, 0, stream>>>(ei, cur, srt, E, N);
  int ngroups = (N + 3) / 4;
  int ggrid = ngroups < 2048 ? ngroups : 2048;
  gatout_kernel<<<ggrid, 256, 0, stream>>>(srt, row, asrc4, adst4, meta_x, W, bias, out, N);
}

// Round 4
// 362.011 us; speedup vs baseline: 1.2109x; 1.2109x over previous
//
#include <hip/hip_runtime.h>
#include <math.h>

#define MAXDEG 192

__device__ __forceinline__ float lrelu(float v) { return v > 0.0f ? v : 0.2f * v; }

// ---- Kernel A: fold attention vectors into W: wsrc[k,h] = sum_c W[k,h*64+c]*att_src[h,c]
__global__ void patt_kernel(const float* __restrict__ W, const float* __restrict__ att_src,
                            const float* __restrict__ att_dst, float* __restrict__ wsrc,
                            float* __restrict__ wdst) {
  int t = threadIdx.x;  // 256 threads: h = t>>6, k = t&63
  int h = t >> 6, k = t & 63;
  const float* wrow = W + (size_t)k * 256 + h * 64;
  const float* as = att_src + h * 64;
  const float* ad = att_dst + h * 64;
  float ss = 0.f, sd = 0.f;
#pragma unroll
  for (int c = 0; c < 64; ++c) {
    float w = wrow[c];
    ss = fmaf(w, as[c], ss);
    sd = fmaf(w, ad[c], sd);
  }
  wsrc[k * 4 + h] = ss;
  wdst[k * 4 + h] = sd;
}

// ---- Kernel B: per-node attention scalars a_src/a_dst = meta_x @ wsrc/wdst  -> [N,4]
__global__ void nattn_kernel(const float* __restrict__ x, const float4* __restrict__ wsrc4,
                             const float4* __restrict__ wdst4, float4* __restrict__ asrc4,
                             float4* __restrict__ adst4, int N) {
  int lane = threadIdx.x & 63;
  int n = blockIdx.x * 4 + (threadIdx.x >> 6);
  if (n >= N) return;
  float xv = x[(size_t)n * 64 + lane];
  float4 ws = wsrc4[lane], wd = wdst4[lane];
  float s0 = xv * ws.x, s1 = xv * ws.y, s2 = xv * ws.z, s3 = xv * ws.w;
  float d0 = xv * wd.x, d1 = xv * wd.y, d2 = xv * wd.z, d3 = xv * wd.w;
#pragma unroll
  for (int m = 1; m < 64; m <<= 1) {
    s0 += __shfl_xor(s0, m, 64); s1 += __shfl_xor(s1, m, 64);
    s2 += __shfl_xor(s2, m, 64); s3 += __shfl_xor(s3, m, 64);
    d0 += __shfl_xor(d0, m, 64); d1 += __shfl_xor(d1, m, 64);
    d2 += __shfl_xor(d2, m, 64); d3 += __shfl_xor(d3, m, 64);
  }
  if (lane == 0) {
    asrc4[n] = make_float4(s0, s1, s2, s3);
    adst4[n] = make_float4(d0, d1, d2, d3);
  }
}

// ---- Kernel C: histogram of destinations (self-loops appended at the end) [round-2 proven]
__global__ void hist_kernel(const int* __restrict__ ei, int* __restrict__ counts,
                            int E, int N) {
  int e = blockIdx.x * 256 + threadIdx.x;
  int ET = E + N;
  if (e >= ET) return;
  int dst = (e < E) ? ei[(size_t)E + e] : (e - E);
  atomicAdd(&counts[dst], 1);
}

// ---- Kernel D: single-block exclusive scan -> row_start[N+1], cursor copy [round-2 proven]
__global__ void scan_kernel(const int* __restrict__ counts, int* __restrict__ row_start,
                            int* __restrict__ cursor, int N) {
  __shared__ int part[1024];
  int t = threadIdx.x;
  int chunk = (N + 1023) >> 10;
  int base = t * chunk;
  int s = 0;
  for (int i = 0; i < chunk; ++i) {
    int idx = base + i;
    if (idx < N) s += counts[idx];
  }
  part[t] = s;
  __syncthreads();
  for (int d = 1; d < 1024; d <<= 1) {
    int v = (t >= d) ? part[t - d] : 0;
    __syncthreads();
    part[t] += v;
    __syncthreads();
  }
  int run = (t == 0) ? 0 : part[t - 1];
  for (int i = 0; i < chunk; ++i) {
    int idx = base + i;
    if (idx < N) {
      row_start[idx] = run;
      cursor[idx] = run;
      run += counts[idx];
      if (idx == N - 1) row_start[N] = run;
    }
  }
}

// ---- Kernel E: scatter edge sources into dst-sorted order [round-2 proven]
__global__ void scatter_kernel(const int* __restrict__ ei, int* __restrict__ cursor,
                               int* __restrict__ src_sorted, int E, int N) {
  int e = blockIdx.x * 256 + threadIdx.x;
  int ET = E + N;
  if (e >= ET) return;
  int src, dst;
  if (e < E) {
    src = ei[e];
    dst = ei[(size_t)E + e];
  } else {
    src = dst = e - E;
  }
  int pos = atomicAdd(&cursor[dst], 1);
  src_sorted[pos] = src;
}

// ---- Fused: per-node softmax (no max-sub; logits are O(1)) + aggregation + projection.
// Block = 4 waves = 4 nodes per group. CSR includes self-loops (round-2 semantics).
__global__ __launch_bounds__(256) void gatout_kernel(
    const int* __restrict__ srt, const int* __restrict__ row,
    const float4* __restrict__ asrc4, const float4* __restrict__ adst4,
    const float* __restrict__ x, const float* __restrict__ W,
    const float* __restrict__ bias, float* __restrict__ out, int N) {
  __shared__ float4 alL[4][MAXDEG];  // per-wave cached exp(logit) per edge
  __shared__ int slL[4][MAXDEG];     // per-wave cached src index per edge
  __shared__ float aggL[4][4][64];   // [node][head][k]
  __shared__ float pL[4][4][64];     // [head][node][c]
  int t = threadIdx.x, w = t >> 6, lane = t & 63;
  float Wreg[64];  // W[k, w*64 + lane]
#pragma unroll
  for (int k = 0; k < 64; ++k) Wreg[k] = W[(size_t)k * 256 + w * 64 + lane];
  float bv = bias[lane];
  int ngroups = (N + 3) >> 2;
  for (int g = blockIdx.x; g < ngroups; g += gridDim.x) {
    int n = g * 4 + w;
    float a0 = 0.f, a1 = 0.f, a2 = 0.f, a3 = 0.f;
    float r0 = 0.f, r1 = 0.f, r2 = 0.f, r3 = 0.f;
    if (n < N) {
      int start = row[n], end = row[n + 1];
      int deg = end - start;
      float4 ad = adst4[n];
      float t0 = 0.f, t1 = 0.f, t2 = 0.f, t3 = 0.f;
      if (deg <= MAXDEG) {
        // Pass A: compute exp(logit), cache in LDS, accumulate sums
        for (int b = 0; b < deg; b += 64) {
          if (b + lane < deg) {
            int sl = srt[start + b + lane];
            float4 as = asrc4[sl];
            float4 e;
            e.x = __expf(lrelu(as.x + ad.x));
            e.y = __expf(lrelu(as.y + ad.y));
            e.z = __expf(lrelu(as.z + ad.z));
            e.w = __expf(lrelu(as.w + ad.w));
            alL[w][b + lane] = e;
            slL[w][b + lane] = sl;
            t0 += e.x; t1 += e.y; t2 += e.z; t3 += e.w;
          }
        }
      } else {
        for (int b = start; b < end; b += 64) {
          int idx = b + lane;
          if (idx < end) {
            int sl = srt[idx];
            float4 as = asrc4[sl];
            t0 += __expf(lrelu(as.x + ad.x));
            t1 += __expf(lrelu(as.y + ad.y));
            t2 += __expf(lrelu(as.z + ad.z));
            t3 += __expf(lrelu(as.w + ad.w));
          }
        }
      }
      // butterfly sum (adds only — no exps)
#pragma unroll
      for (int m = 1; m < 64; m <<= 1) {
        t0 += __shfl_xor(t0, m, 64);
        t1 += __shfl_xor(t1, m, 64);
        t2 += __shfl_xor(t2, m, 64);
        t3 += __shfl_xor(t3, m, 64);
      }
      r0 = 0.25f / (t0 + 1e-16f); r1 = 0.25f / (t1 + 1e-16f);
      r2 = 0.25f / (t2 + 1e-16f); r3 = 0.25f / (t3 + 1e-16f);
      // Pass B: weighted aggregation (lane = channel), alphas replayed from LDS
      if (deg <= MAXDEG) {
        int j = 0;
        for (; j + 4 <= deg; j += 4) {
          float4 e0 = alL[w][j], e1 = alL[w][j + 1], e2 = alL[w][j + 2], e3 = alL[w][j + 3];
          int q0 = slL[w][j], q1 = slL[w][j + 1], q2 = slL[w][j + 2], q3 = slL[w][j + 3];
          float v0 = x[(size_t)q0 * 64 + lane];
          float v1 = x[(size_t)q1 * 64 + lane];
          float v2 = x[(size_t)q2 * 64 + lane];
          float v3 = x[(size_t)q3 * 64 + lane];
          a0 = fmaf(e0.x, v0, a0); a1 = fmaf(e0.y, v0, a1);
          a2 = fmaf(e0.z, v0, a2); a3 = fmaf(e0.w, v0, a3);
          a0 = fmaf(e1.x, v1, a0); a1 = fmaf(e1.y, v1, a1);
          a2 = fmaf(e1.z, v1, a2); a3 = fmaf(e1.w, v1, a3);
          a0 = fmaf(e2.x, v2, a0); a1 = fmaf(e2.y, v2, a1);
          a2 = fmaf(e2.z, v2, a2); a3 = fmaf(e2.w, v2, a3);
          a0 = fmaf(e3.x, v3, a0); a1 = fmaf(e3.y, v3, a1);
          a2 = fmaf(e3.z, v3, a2); a3 = fmaf(e3.w, v3, a3);
        }
        for (; j < deg; ++j) {
          float4 e0 = alL[w][j];
          int q0 = slL[w][j];
          float v0 = x[(size_t)q0 * 64 + lane];
          a0 = fmaf(e0.x, v0, a0); a1 = fmaf(e0.y, v0, a1);
          a2 = fmaf(e0.z, v0, a2); a3 = fmaf(e0.w, v0, a3);
        }
      } else {
        for (int b = start; b < end; b += 64) {
          int cnt = end - b;
          if (cnt > 64) cnt = 64;
          int idx = b + lane;
          int sl = 0;
          float e0 = 0.f, e1 = 0.f, e2 = 0.f, e3 = 0.f;
          if (idx < end) {
            sl = srt[idx];
            float4 as = asrc4[sl];
            e0 = __expf(lrelu(as.x + ad.x));
            e1 = __expf(lrelu(as.y + ad.y));
            e2 = __expf(lrelu(as.z + ad.z));
            e3 = __expf(lrelu(as.w + ad.w));
          }
          for (int j = 0; j < cnt; ++j) {
            int sj = __shfl(sl, j, 64);
            float b0 = __shfl(e0, j, 64), b1 = __shfl(e1, j, 64);
            float b2 = __shfl(e2, j, 64), b3 = __shfl(e3, j, 64);
            float v = x[(size_t)sj * 64 + lane];
            a0 = fmaf(b0, v, a0); a1 = fmaf(b1, v, a1);
            a2 = fmaf(b2, v, a2); a3 = fmaf(b3, v, a3);
          }
        }
      }
    }
    __syncthreads();  // previous group's phase 2 done with aggL
    aggL[w][0][lane] = a0 * r0;
    aggL[w][1][lane] = a1 * r1;
    aggL[w][2][lane] = a2 * r2;
    aggL[w][3][lane] = a3 * r3;
    __syncthreads();
    // Phase 2: wave w = head w. pL[w][i][c] = sum_k aggL[i][w][k] * W[k, w*64+c]
#pragma unroll
    for (int i = 0; i < 4; ++i) {
      float acc = 0.f;
#pragma unroll
      for (int k4 = 0; k4 < 16; ++k4) {
        float4 av = *(const float4*)&aggL[i][w][k4 * 4];
        acc = fmaf(av.x, Wreg[k4 * 4 + 0], acc);
        acc = fmaf(av.y, Wreg[k4 * 4 + 1], acc);
        acc = fmaf(av.z, Wreg[k4 * 4 + 2], acc);
        acc = fmaf(av.w, Wreg[k4 * 4 + 3], acc);
      }
      pL[w][i][lane] = acc;
    }
    __syncthreads();
    if (n < N) {
      out[(size_t)n * 64 + lane] = pL[0][w][lane] + pL[1][w][lane] +
                                   pL[2][w][lane] + pL[3][w][lane] + bv;
    }
  }
}

extern "C" void kernel_launch(void* const* d_in, const int* in_sizes, int n_in,
                              void* d_out, int out_size, void* d_ws, size_t ws_size,
                              hipStream_t stream) {
  const float* meta_x = (const float*)d_in[0];
  const int* ei = (const int*)d_in[1];  // int32 edge index [2,E] flat
  const float* W = (const float*)d_in[2];
  const float* att_src = (const float*)d_in[3];
  const float* att_dst = (const float*)d_in[4];
  const float* bias = (const float*)d_in[5];
  float* out = (float*)d_out;

  int N = in_sizes[0] / 64;
  int E = in_sizes[1] / 2;
  int ET = E + N;

  char* ws = (char*)d_ws;
  size_t off = 0;
  auto alloc = [&](size_t bytes) {
    size_t o = off;
    off += (bytes + 255) & ~(size_t)255;
    return o;
  };
  size_t o_wsrc = alloc(64 * 4 * sizeof(float));
  size_t o_wdst = alloc(64 * 4 * sizeof(float));
  size_t o_asrc = alloc((size_t)N * 4 * sizeof(float));
  size_t o_adst = alloc((size_t)N * 4 * sizeof(float));
  size_t o_cnt = alloc((size_t)N * sizeof(int));
  size_t o_row = alloc(((size_t)N + 1) * sizeof(int));
  size_t o_cur = alloc((size_t)N * sizeof(int));
  size_t o_srt = alloc((size_t)ET * sizeof(int));
  (void)ws_size;  // ~5.6 MB total

  float* wsrc = (float*)(ws + o_wsrc);
  float* wdst = (float*)(ws + o_wdst);
  float4* asrc4 = (float4*)(ws + o_asrc);
  float4* adst4 = (float4*)(ws + o_adst);
  int* cnt = (int*)(ws + o_cnt);
  int* row = (int*)(ws + o_row);
  int* cur = (int*)(ws + o_cur);
  int* srt = (int*)(ws + o_srt);

  hipMemsetAsync(cnt, 0, (size_t)N * sizeof(int), stream);

  patt_kernel<<<1, 256, 0, stream>>>(W, att_src, att_dst, wsrc, wdst);
  nattn_kernel<<<(N + 3) / 4, 256, 0, stream>>>(meta_x, (const float4*)wsrc,
                                                (const float4*)wdst, asrc4, adst4, N);
  hist_kernel<<<(ET + 255) / 256, 256, 0, stream>>>(ei, cnt, E, N);
  scan_kernel<<<1, 1024, 0, stream>>>(cnt, row, cur, N);
  scatter_kernel<<<(ET + 255) / 256, 256, 0, stream>>>(ei, cur, srt, E, N);
  int ngroups = (N + 3) / 4;
  int ggrid = ngroups < 2048 ? ngroups : 2048;
  gatout_kernel<<<ggrid, 256, 0, stream>>>(srt, row, asrc4, adst4, meta_x, W, bias, out, N);
}

// Round 5
// 244.757 us; speedup vs baseline: 1.7910x; 1.4791x over previous
//
#include <hip/hip_runtime.h>
#include <math.h>

#define MAXDEG 192

__device__ __forceinline__ float lrelu(float v) { return v > 0.0f ? v : 0.2f * v; }

// ---- Kernel A: fold attention vectors into W: wsrc[k,h] = sum_c W[k,h*64+c]*att_src[h,c]
__global__ void patt_kernel(const float* __restrict__ W, const float* __restrict__ att_src,
                            const float* __restrict__ att_dst, float* __restrict__ wsrc,
                            float* __restrict__ wdst) {
  int t = threadIdx.x;  // 256 threads: h = t>>6, k = t&63
  int h = t >> 6, k = t & 63;
  const float* wrow = W + (size_t)k * 256 + h * 64;
  const float* as = att_src + h * 64;
  const float* ad = att_dst + h * 64;
  float ss = 0.f, sd = 0.f;
#pragma unroll
  for (int c = 0; c < 64; ++c) {
    float w = wrow[c];
    ss = fmaf(w, as[c], ss);
    sd = fmaf(w, ad[c], sd);
  }
  wsrc[k * 4 + h] = ss;
  wdst[k * 4 + h] = sd;
}

// ---- Kernel B: per-node attention scalars a_src/a_dst = meta_x @ wsrc/wdst  -> [N,4]
__global__ void nattn_kernel(const float* __restrict__ x, const float4* __restrict__ wsrc4,
                             const float4* __restrict__ wdst4, float4* __restrict__ asrc4,
                             float4* __restrict__ adst4, int N) {
  int lane = threadIdx.x & 63;
  int n = blockIdx.x * 4 + (threadIdx.x >> 6);
  if (n >= N) return;
  float xv = x[(size_t)n * 64 + lane];
  float4 ws = wsrc4[lane], wd = wdst4[lane];
  float s0 = xv * ws.x, s1 = xv * ws.y, s2 = xv * ws.z, s3 = xv * ws.w;
  float d0 = xv * wd.x, d1 = xv * wd.y, d2 = xv * wd.z, d3 = xv * wd.w;
#pragma unroll
  for (int m = 1; m < 64; m <<= 1) {
    s0 += __shfl_xor(s0, m, 64); s1 += __shfl_xor(s1, m, 64);
    s2 += __shfl_xor(s2, m, 64); s3 += __shfl_xor(s3, m, 64);
    d0 += __shfl_xor(d0, m, 64); d1 += __shfl_xor(d1, m, 64);
    d2 += __shfl_xor(d2, m, 64); d3 += __shfl_xor(d3, m, 64);
  }
  if (lane == 0) {
    asrc4[n] = make_float4(s0, s1, s2, s3);
    adst4[n] = make_float4(d0, d1, d2, d3);
  }
}

// ---- Kernel C: histogram of destinations (self-loops appended at the end) [round-2 proven]
__global__ void hist_kernel(const int* __restrict__ ei, int* __restrict__ counts,
                            int E, int N) {
  int e = blockIdx.x * 256 + threadIdx.x;
  int ET = E + N;
  if (e >= ET) return;
  int dst = (e < E) ? ei[(size_t)E + e] : (e - E);
  atomicAdd(&counts[dst], 1);
}

// ---- Hierarchical scan, phase A: per-tile (256 counts) sums. Coalesced.
__global__ void scanA_kernel(const int* __restrict__ cnt, int* __restrict__ tsum, int N) {
  int b = blockIdx.x, t = threadIdx.x;
  int idx = b * 256 + t;
  int v = (idx < N) ? cnt[idx] : 0;
#pragma unroll
  for (int m = 1; m < 64; m <<= 1) v += __shfl_xor(v, m, 64);
  __shared__ int ws[4];
  if ((t & 63) == 0) ws[t >> 6] = v;
  __syncthreads();
  if (t == 0) tsum[b] = ws[0] + ws[1] + ws[2] + ws[3];
}

// ---- Phase B: exclusive scan of tile sums (one block, LDS Hillis-Steele, chunked w/ carry)
__global__ void scanB_kernel(int* __restrict__ tsum, int ntiles) {
  __shared__ int part[256];
  int t = threadIdx.x;
  int carry = 0;
  for (int b0 = 0; b0 < ntiles; b0 += 256) {
    int idx = b0 + t;
    int v = (idx < ntiles) ? tsum[idx] : 0;
    part[t] = v;
    __syncthreads();
    for (int d = 1; d < 256; d <<= 1) {
      int u = (t >= d) ? part[t - d] : 0;
      __syncthreads();
      part[t] += u;
      __syncthreads();
    }
    if (idx < ntiles) tsum[idx] = part[t] - v + carry;  // exclusive + carry
    carry += part[255];
    __syncthreads();
  }
}

// ---- Phase C: intra-tile exclusive scan + tile offset -> row_start, cursor
__global__ void scanC_kernel(const int* __restrict__ cnt, const int* __restrict__ tsum,
                             int* __restrict__ row, int* __restrict__ cur, int N) {
  __shared__ int part[256];
  int b = blockIdx.x, t = threadIdx.x;
  int idx = b * 256 + t;
  int c = (idx < N) ? cnt[idx] : 0;
  part[t] = c;
  __syncthreads();
  for (int d = 1; d < 256; d <<= 1) {
    int u = (t >= d) ? part[t - d] : 0;
    __syncthreads();
    part[t] += u;
    __syncthreads();
  }
  int exc = part[t] - c + tsum[b];
  if (idx < N) {
    row[idx] = exc;
    cur[idx] = exc;
    if (idx == N - 1) row[N] = exc + c;
  }
}

// ---- Kernel E: scatter edge sources into dst-sorted order [round-2 proven]
__global__ void scatter_kernel(const int* __restrict__ ei, int* __restrict__ cursor,
                               int* __restrict__ src_sorted, int E, int N) {
  int e = blockIdx.x * 256 + threadIdx.x;
  int ET = E + N;
  if (e >= ET) return;
  int src, dst;
  if (e < E) {
    src = ei[e];
    dst = ei[(size_t)E + e];
  } else {
    src = dst = e - E;
  }
  int pos = atomicAdd(&cursor[dst], 1);
  src_sorted[pos] = src;
}

// ---- Fused: per-node softmax (no max-sub; logits are O(1)) + aggregation + projection.
// Block = 4 waves = 4 nodes per group. CSR includes self-loops (round-2 semantics).
__global__ __launch_bounds__(256) void gatout_kernel(
    const int* __restrict__ srt, const int* __restrict__ row,
    const float4* __restrict__ asrc4, const float4* __restrict__ adst4,
    const float* __restrict__ x, const float* __restrict__ W,
    const float* __restrict__ bias, float* __restrict__ out, int N) {
  __shared__ float4 alL[4][MAXDEG];  // per-wave cached exp(logit) per edge
  __shared__ int slL[4][MAXDEG];     // per-wave cached src index per edge
  __shared__ float aggL[4][4][64];   // [node][head][k]
  __shared__ float pL[4][4][64];     // [head][node][c]
  int t = threadIdx.x, w = t >> 6, lane = t & 63;
  float Wreg[64];  // W[k, w*64 + lane]
#pragma unroll
  for (int k = 0; k < 64; ++k) Wreg[k] = W[(size_t)k * 256 + w * 64 + lane];
  float bv = bias[lane];
  int ngroups = (N + 3) >> 2;
  for (int g = blockIdx.x; g < ngroups; g += gridDim.x) {
    int n = g * 4 + w;
    float a0 = 0.f, a1 = 0.f, a2 = 0.f, a3 = 0.f;
    float r0 = 0.f, r1 = 0.f, r2 = 0.f, r3 = 0.f;
    if (n < N) {
      int start = row[n], end = row[n + 1];
      int deg = end - start;
      float4 ad = adst4[n];
      float t0 = 0.f, t1 = 0.f, t2 = 0.f, t3 = 0.f;
      if (deg <= MAXDEG) {
        // Pass A: compute exp(logit), cache in LDS, accumulate sums
        for (int b = 0; b < deg; b += 64) {
          if (b + lane < deg) {
            int sl = srt[start + b + lane];
            float4 as = asrc4[sl];
            float4 e;
            e.x = __expf(lrelu(as.x + ad.x));
            e.y = __expf(lrelu(as.y + ad.y));
            e.z = __expf(lrelu(as.z + ad.z));
            e.w = __expf(lrelu(as.w + ad.w));
            alL[w][b + lane] = e;
            slL[w][b + lane] = sl;
            t0 += e.x; t1 += e.y; t2 += e.z; t3 += e.w;
          }
        }
      } else {
        for (int b = start; b < end; b += 64) {
          int idx = b + lane;
          if (idx < end) {
            int sl = srt[idx];
            float4 as = asrc4[sl];
            t0 += __expf(lrelu(as.x + ad.x));
            t1 += __expf(lrelu(as.y + ad.y));
            t2 += __expf(lrelu(as.z + ad.z));
            t3 += __expf(lrelu(as.w + ad.w));
          }
        }
      }
      // butterfly sum (adds only — no exps)
#pragma unroll
      for (int m = 1; m < 64; m <<= 1) {
        t0 += __shfl_xor(t0, m, 64);
        t1 += __shfl_xor(t1, m, 64);
        t2 += __shfl_xor(t2, m, 64);
        t3 += __shfl_xor(t3, m, 64);
      }
      r0 = 0.25f / (t0 + 1e-16f); r1 = 0.25f / (t1 + 1e-16f);
      r2 = 0.25f / (t2 + 1e-16f); r3 = 0.25f / (t3 + 1e-16f);
      // Pass B: weighted aggregation (lane = channel), alphas replayed from LDS
      if (deg <= MAXDEG) {
        int j = 0;
        for (; j + 4 <= deg; j += 4) {
          float4 e0 = alL[w][j], e1 = alL[w][j + 1], e2 = alL[w][j + 2], e3 = alL[w][j + 3];
          int q0 = slL[w][j], q1 = slL[w][j + 1], q2 = slL[w][j + 2], q3 = slL[w][j + 3];
          float v0 = x[(size_t)q0 * 64 + lane];
          float v1 = x[(size_t)q1 * 64 + lane];
          float v2 = x[(size_t)q2 * 64 + lane];
          float v3 = x[(size_t)q3 * 64 + lane];
          a0 = fmaf(e0.x, v0, a0); a1 = fmaf(e0.y, v0, a1);
          a2 = fmaf(e0.z, v0, a2); a3 = fmaf(e0.w, v0, a3);
          a0 = fmaf(e1.x, v1, a0); a1 = fmaf(e1.y, v1, a1);
          a2 = fmaf(e1.z, v1, a2); a3 = fmaf(e1.w, v1, a3);
          a0 = fmaf(e2.x, v2, a0); a1 = fmaf(e2.y, v2, a1);
          a2 = fmaf(e2.z, v2, a2); a3 = fmaf(e2.w, v2, a3);
          a0 = fmaf(e3.x, v3, a0); a1 = fmaf(e3.y, v3, a1);
          a2 = fmaf(e3.z, v3, a2); a3 = fmaf(e3.w, v3, a3);
        }
        for (; j < deg; ++j) {
          float4 e0 = alL[w][j];
          int q0 = slL[w][j];
          float v0 = x[(size_t)q0 * 64 + lane];
          a0 = fmaf(e0.x, v0, a0); a1 = fmaf(e0.y, v0, a1);
          a2 = fmaf(e0.z, v0, a2); a3 = fmaf(e0.w, v0, a3);
        }
      } else {
        for (int b = start; b < end; b += 64) {
          int cnt = end - b;
          if (cnt > 64) cnt = 64;
          int idx = b + lane;
          int sl = 0;
          float e0 = 0.f, e1 = 0.f, e2 = 0.f, e3 = 0.f;
          if (idx < end) {
            sl = srt[idx];
            float4 as = asrc4[sl];
            e0 = __expf(lrelu(as.x + ad.x));
            e1 = __expf(lrelu(as.y + ad.y));
            e2 = __expf(lrelu(as.z + ad.z));
            e3 = __expf(lrelu(as.w + ad.w));
          }
          for (int j = 0; j < cnt; ++j) {
            int sj = __shfl(sl, j, 64);
            float b0 = __shfl(e0, j, 64), b1 = __shfl(e1, j, 64);
            float b2 = __shfl(e2, j, 64), b3 = __shfl(e3, j, 64);
            float v = x[(size_t)sj * 64 + lane];
            a0 = fmaf(b0, v, a0); a1 = fmaf(b1, v, a1);
            a2 = fmaf(b2, v, a2); a3 = fmaf(b3, v, a3);
          }
        }
      }
    }
    __syncthreads();  // previous group's phase 2 done with aggL
    aggL[w][0][lane] = a0 * r0;
    aggL[w][1][lane] = a1 * r1;
    aggL[w][2][lane] = a2 * r2;
    aggL[w][3][lane] = a3 * r3;
    __syncthreads();
    // Phase 2: wave w = head w. pL[w][i][c] = sum_k aggL[i][w][k] * W[k, w*64+c]
#pragma unroll
    for (int i = 0; i < 4; ++i) {
      float acc = 0.f;
#pragma unroll
      for (int k4 = 0; k4 < 16; ++k4) {
        float4 av = *(const float4*)&aggL[i][w][k4 * 4];
        acc = fmaf(av.x, Wreg[k4 * 4 + 0], acc);
        acc = fmaf(av.y, Wreg[k4 * 4 + 1], acc);
        acc = fmaf(av.z, Wreg[k4 * 4 + 2], acc);
        acc = fmaf(av.w, Wreg[k4 * 4 + 3], acc);
      }
      pL[w][i][lane] = acc;
    }
    __syncthreads();
    if (n < N) {
      out[(size_t)n * 64 + lane] = pL[0][w][lane] + pL[1][w][lane] +
                                   pL[2][w][lane] + pL[3][w][lane] + bv;
    }
  }
}

extern "C" void kernel_launch(void* const* d_in, const int* in_sizes, int n_in,
                              void* d_out, int out_size, void* d_ws, size_t ws_size,
                              hipStream_t stream) {
  const float* meta_x = (const float*)d_in[0];
  const int* ei = (const int*)d_in[1];  // int32 edge index [2,E] flat
  const float* W = (const float*)d_in[2];
  const float* att_src = (const float*)d_in[3];
  const float* att_dst = (const float*)d_in[4];
  const float* bias = (const float*)d_in[5];
  float* out = (float*)d_out;

  int N = in_sizes[0] / 64;
  int E = in_sizes[1] / 2;
  int ET = E + N;

  char* ws = (char*)d_ws;
  size_t off = 0;
  auto alloc = [&](size_t bytes) {
    size_t o = off;
    off += (bytes + 255) & ~(size_t)255;
    return o;
  };
  size_t o_wsrc = alloc(64 * 4 * sizeof(float));
  size_t o_wdst = alloc(64 * 4 * sizeof(float));
  size_t o_asrc = alloc((size_t)N * 4 * sizeof(float));
  size_t o_adst = alloc((size_t)N * 4 * sizeof(float));
  size_t o_cnt = alloc((size_t)N * sizeof(int));
  size_t o_row = alloc(((size_t)N + 1) * sizeof(int));
  size_t o_cur = alloc((size_t)N * sizeof(int));
  size_t o_srt = alloc((size_t)ET * sizeof(int));
  size_t o_ts = alloc((((size_t)N + 255) / 256) * sizeof(int));
  (void)ws_size;  // ~5.6 MB total

  float* wsrc = (float*)(ws + o_wsrc);
  float* wdst = (float*)(ws + o_wdst);
  float4* asrc4 = (float4*)(ws + o_asrc);
  float4* adst4 = (float4*)(ws + o_adst);
  int* cnt = (int*)(ws + o_cnt);
  int* row = (int*)(ws + o_row);
  int* cur = (int*)(ws + o_cur);
  int* srt = (int*)(ws + o_srt);
  int* tsum = (int*)(ws + o_ts);

  hipMemsetAsync(cnt, 0, (size_t)N * sizeof(int), stream);

  patt_kernel<<<1, 256, 0, stream>>>(W, att_src, att_dst, wsrc, wdst);
  nattn_kernel<<<(N + 3) / 4, 256, 0, stream>>>(meta_x, (const float4*)wsrc,
                                                (const float4*)wdst, asrc4, adst4, N);
  hist_kernel<<<(ET + 255) / 256, 256, 0, stream>>>(ei, cnt, E, N);
  int ntiles = (N + 255) / 256;
  scanA_kernel<<<ntiles, 256, 0, stream>>>(cnt, tsum, N);
  scanB_kernel<<<1, 256, 0, stream>>>(tsum, ntiles);
  scanC_kernel<<<ntiles, 256, 0, stream>>>(cnt, tsum, row, cur, N);
  scatter_kernel<<<(ET + 255) / 256, 256, 0, stream>>>(ei, cur, srt, E, N);
  int ngroups = (N + 3) / 4;
  int ggrid = ngroups < 2048 ? ngroups : 2048;
  gatout_kernel<<<ggrid, 256, 0, stream>>>(srt, row, asrc4, adst4, meta_x, W, bias, out, N);
}

// Round 6
// 224.085 us; speedup vs baseline: 1.9563x; 1.0923x over previous
//
#include <hip/hip_runtime.h>
#include <math.h>

#define MAXDEG 64

__device__ __forceinline__ float lrelu(float v) { return v > 0.0f ? v : 0.2f * v; }

// ---- Kernel A: fold attention vectors into W: wsrc[k,h] = sum_c W[k,h*64+c]*att_src[h,c]
__global__ void patt_kernel(const float* __restrict__ W, const float* __restrict__ att_src,
                            const float* __restrict__ att_dst, float* __restrict__ wsrc,
                            float* __restrict__ wdst) {
  int t = threadIdx.x;  // 256 threads: h = t>>6, k = t&63
  int h = t >> 6, k = t & 63;
  const float* wrow = W + (size_t)k * 256 + h * 64;
  const float* as = att_src + h * 64;
  const float* ad = att_dst + h * 64;
  float ss = 0.f, sd = 0.f;
#pragma unroll
  for (int c = 0; c < 64; ++c) {
    float w = wrow[c];
    ss = fmaf(w, as[c], ss);
    sd = fmaf(w, ad[c], sd);
  }
  wsrc[k * 4 + h] = ss;
  wdst[k * 4 + h] = sd;
}

// ---- Kernel B: per-node attention scalars a_src/a_dst = meta_x @ wsrc/wdst  -> [N,4]
__global__ void nattn_kernel(const float* __restrict__ x, const float4* __restrict__ wsrc4,
                             const float4* __restrict__ wdst4, float4* __restrict__ asrc4,
                             float4* __restrict__ adst4, int N) {
  int lane = threadIdx.x & 63;
  int n = blockIdx.x * 4 + (threadIdx.x >> 6);
  if (n >= N) return;
  float xv = x[(size_t)n * 64 + lane];
  float4 ws = wsrc4[lane], wd = wdst4[lane];
  float s0 = xv * ws.x, s1 = xv * ws.y, s2 = xv * ws.z, s3 = xv * ws.w;
  float d0 = xv * wd.x, d1 = xv * wd.y, d2 = xv * wd.z, d3 = xv * wd.w;
#pragma unroll
  for (int m = 1; m < 64; m <<= 1) {
    s0 += __shfl_xor(s0, m, 64); s1 += __shfl_xor(s1, m, 64);
    s2 += __shfl_xor(s2, m, 64); s3 += __shfl_xor(s3, m, 64);
    d0 += __shfl_xor(d0, m, 64); d1 += __shfl_xor(d1, m, 64);
    d2 += __shfl_xor(d2, m, 64); d3 += __shfl_xor(d3, m, 64);
  }
  if (lane == 0) {
    asrc4[n] = make_float4(s0, s1, s2, s3);
    adst4[n] = make_float4(d0, d1, d2, d3);
  }
}

// ---- Kernel C: histogram of destinations (self-loops appended at the end) [proven]
__global__ void hist_kernel(const int* __restrict__ ei, int* __restrict__ counts,
                            int E, int N) {
  int e = blockIdx.x * 256 + threadIdx.x;
  int ET = E + N;
  if (e >= ET) return;
  int dst = (e < E) ? ei[(size_t)E + e] : (e - E);
  atomicAdd(&counts[dst], 1);
}

// ---- Hierarchical scan, phase A: per-tile (256 counts) sums. Coalesced. [proven r5]
__global__ void scanA_kernel(const int* __restrict__ cnt, int* __restrict__ tsum, int N) {
  int b = blockIdx.x, t = threadIdx.x;
  int idx = b * 256 + t;
  int v = (idx < N) ? cnt[idx] : 0;
#pragma unroll
  for (int m = 1; m < 64; m <<= 1) v += __shfl_xor(v, m, 64);
  __shared__ int ws[4];
  if ((t & 63) == 0) ws[t >> 6] = v;
  __syncthreads();
  if (t == 0) tsum[b] = ws[0] + ws[1] + ws[2] + ws[3];
}

// ---- Phase B: exclusive scan of tile sums [proven r5]
__global__ void scanB_kernel(int* __restrict__ tsum, int ntiles) {
  __shared__ int part[256];
  int t = threadIdx.x;
  int carry = 0;
  for (int b0 = 0; b0 < ntiles; b0 += 256) {
    int idx = b0 + t;
    int v = (idx < ntiles) ? tsum[idx] : 0;
    part[t] = v;
    __syncthreads();
    for (int d = 1; d < 256; d <<= 1) {
      int u = (t >= d) ? part[t - d] : 0;
      __syncthreads();
      part[t] += u;
      __syncthreads();
    }
    if (idx < ntiles) tsum[idx] = part[t] - v + carry;  // exclusive + carry
    carry += part[255];
    __syncthreads();
  }
}

// ---- Phase C: intra-tile exclusive scan + tile offset -> row_start, cursor [proven r5]
__global__ void scanC_kernel(const int* __restrict__ cnt, const int* __restrict__ tsum,
                             int* __restrict__ row, int* __restrict__ cur, int N) {
  __shared__ int part[256];
  int b = blockIdx.x, t = threadIdx.x;
  int idx = b * 256 + t;
  int c = (idx < N) ? cnt[idx] : 0;
  part[t] = c;
  __syncthreads();
  for (int d = 1; d < 256; d <<= 1) {
    int u = (t >= d) ? part[t - d] : 0;
    __syncthreads();
    part[t] += u;
    __syncthreads();
  }
  int exc = part[t] - c + tsum[b];
  if (idx < N) {
    row[idx] = exc;
    cur[idx] = exc;
    if (idx == N - 1) row[N] = exc + c;
  }
}

// ---- Kernel E: scatter edge sources into dst-sorted order [proven]
__global__ void scatter_kernel(const int* __restrict__ ei, int* __restrict__ cursor,
                               int* __restrict__ src_sorted, int E, int N) {
  int e = blockIdx.x * 256 + threadIdx.x;
  int ET = E + N;
  if (e >= ET) return;
  int src, dst;
  if (e < E) {
    src = ei[e];
    dst = ei[(size_t)E + e];
  } else {
    src = dst = e - E;
  }
  int pos = atomicAdd(&cursor[dst], 1);
  src_sorted[pos] = src;
}

// ---- Fused: per-node softmax + aggregation + projection.
// LDS shrunk to 9216B for occupancy: MAXDEG=64 and pL aliased into aggL (buf).
// Block = 4 waves = 4 nodes per group; CSR includes self-loops.
__global__ __launch_bounds__(256) void gatout_kernel(
    const int* __restrict__ srt, const int* __restrict__ row,
    const float4* __restrict__ asrc4, const float4* __restrict__ adst4,
    const float* __restrict__ x, const float* __restrict__ W,
    const float* __restrict__ bias, float* __restrict__ out, int N) {
  __shared__ float4 alL[4][MAXDEG];  // per-wave cached exp(logit) per edge (4096B)
  __shared__ int slL[4][MAXDEG];     // per-wave cached src index per edge (1024B)
  __shared__ float buf[4][4][64];    // phase1: agg[node][head][k]; phase2: p[head][node][c]
  int t = threadIdx.x, w = t >> 6, lane = t & 63;
  float Wreg[64];  // W[k, w*64 + lane]
#pragma unroll
  for (int k = 0; k < 64; ++k) Wreg[k] = W[(size_t)k * 256 + w * 64 + lane];
  float bv = bias[lane];
  int ngroups = (N + 3) >> 2;
  for (int g = blockIdx.x; g < ngroups; g += gridDim.x) {
    int n = g * 4 + w;
    float a0 = 0.f, a1 = 0.f, a2 = 0.f, a3 = 0.f;
    float r0 = 0.f, r1 = 0.f, r2 = 0.f, r3 = 0.f;
    if (n < N) {
      int start = row[n], end = row[n + 1];
      int deg = end - start;
      float4 ad = adst4[n];
      float t0 = 0.f, t1 = 0.f, t2 = 0.f, t3 = 0.f;
      if (deg <= MAXDEG) {
        // Pass A: compute exp(logit), cache in LDS (same-wave use only), accumulate sums
        for (int b = 0; b < deg; b += 64) {
          if (b + lane < deg) {
            int sl = srt[start + b + lane];
            float4 as = asrc4[sl];
            float4 e;
            e.x = __expf(lrelu(as.x + ad.x));
            e.y = __expf(lrelu(as.y + ad.y));
            e.z = __expf(lrelu(as.z + ad.z));
            e.w = __expf(lrelu(as.w + ad.w));
            alL[w][b + lane] = e;
            slL[w][b + lane] = sl;
            t0 += e.x; t1 += e.y; t2 += e.z; t3 += e.w;
          }
        }
      } else {
        for (int b = start; b < end; b += 64) {
          int idx = b + lane;
          if (idx < end) {
            int sl = srt[idx];
            float4 as = asrc4[sl];
            t0 += __expf(lrelu(as.x + ad.x));
            t1 += __expf(lrelu(as.y + ad.y));
            t2 += __expf(lrelu(as.z + ad.z));
            t3 += __expf(lrelu(as.w + ad.w));
          }
        }
      }
      // butterfly sum (adds only — no exps)
#pragma unroll
      for (int m = 1; m < 64; m <<= 1) {
        t0 += __shfl_xor(t0, m, 64);
        t1 += __shfl_xor(t1, m, 64);
        t2 += __shfl_xor(t2, m, 64);
        t3 += __shfl_xor(t3, m, 64);
      }
      r0 = 0.25f / (t0 + 1e-16f); r1 = 0.25f / (t1 + 1e-16f);
      r2 = 0.25f / (t2 + 1e-16f); r3 = 0.25f / (t3 + 1e-16f);
      // Pass B: weighted aggregation (lane = channel), alphas replayed from LDS
      if (deg <= MAXDEG) {
        int j = 0;
        for (; j + 4 <= deg; j += 4) {
          float4 e0 = alL[w][j], e1 = alL[w][j + 1], e2 = alL[w][j + 2], e3 = alL[w][j + 3];
          int q0 = slL[w][j], q1 = slL[w][j + 1], q2 = slL[w][j + 2], q3 = slL[w][j + 3];
          float v0 = x[(size_t)q0 * 64 + lane];
          float v1 = x[(size_t)q1 * 64 + lane];
          float v2 = x[(size_t)q2 * 64 + lane];
          float v3 = x[(size_t)q3 * 64 + lane];
          a0 = fmaf(e0.x, v0, a0); a1 = fmaf(e0.y, v0, a1);
          a2 = fmaf(e0.z, v0, a2); a3 = fmaf(e0.w, v0, a3);
          a0 = fmaf(e1.x, v1, a0); a1 = fmaf(e1.y, v1, a1);
          a2 = fmaf(e1.z, v1, a2); a3 = fmaf(e1.w, v1, a3);
          a0 = fmaf(e2.x, v2, a0); a1 = fmaf(e2.y, v2, a1);
          a2 = fmaf(e2.z, v2, a2); a3 = fmaf(e2.w, v2, a3);
          a0 = fmaf(e3.x, v3, a0); a1 = fmaf(e3.y, v3, a1);
          a2 = fmaf(e3.z, v3, a2); a3 = fmaf(e3.w, v3, a3);
        }
        for (; j < deg; ++j) {
          float4 e0 = alL[w][j];
          int q0 = slL[w][j];
          float v0 = x[(size_t)q0 * 64 + lane];
          a0 = fmaf(e0.x, v0, a0); a1 = fmaf(e0.y, v0, a1);
          a2 = fmaf(e0.z, v0, a2); a3 = fmaf(e0.w, v0, a3);
        }
      } else {
        for (int b = start; b < end; b += 64) {
          int cnt = end - b;
          if (cnt > 64) cnt = 64;
          int idx = b + lane;
          int sl = 0;
          float e0 = 0.f, e1 = 0.f, e2 = 0.f, e3 = 0.f;
          if (idx < end) {
            sl = srt[idx];
            float4 as = asrc4[sl];
            e0 = __expf(lrelu(as.x + ad.x));
            e1 = __expf(lrelu(as.y + ad.y));
            e2 = __expf(lrelu(as.z + ad.z));
            e3 = __expf(lrelu(as.w + ad.w));
          }
          for (int j = 0; j < cnt; ++j) {
            int sj = __shfl(sl, j, 64);
            float b0 = __shfl(e0, j, 64), b1 = __shfl(e1, j, 64);
            float b2 = __shfl(e2, j, 64), b3 = __shfl(e3, j, 64);
            float v = x[(size_t)sj * 64 + lane];
            a0 = fmaf(b0, v, a0); a1 = fmaf(b1, v, a1);
            a2 = fmaf(b2, v, a2); a3 = fmaf(b3, v, a3);
          }
        }
      }
    }
    __syncthreads();  // previous iteration's final buf reads done
    buf[w][0][lane] = a0 * r0;   // agg layout [node][head][k]
    buf[w][1][lane] = a1 * r1;
    buf[w][2][lane] = a2 * r2;
    buf[w][3][lane] = a3 * r3;
    __syncthreads();
    // Phase 2: wave w = head w. acc[i] = sum_k agg[i][w][k] * W[k, w*64+c] (registers)
    float acc0 = 0.f, acc1 = 0.f, acc2 = 0.f, acc3 = 0.f;
#pragma unroll
    for (int k4 = 0; k4 < 16; ++k4) {
      float4 av0 = *(const float4*)&buf[0][w][k4 * 4];
      float4 av1 = *(const float4*)&buf[1][w][k4 * 4];
      float4 av2 = *(const float4*)&buf[2][w][k4 * 4];
      float4 av3 = *(const float4*)&buf[3][w][k4 * 4];
      float w0 = Wreg[k4 * 4 + 0], w1 = Wreg[k4 * 4 + 1];
      float w2 = Wreg[k4 * 4 + 2], w3 = Wreg[k4 * 4 + 3];
      acc0 = fmaf(av0.x, w0, acc0); acc0 = fmaf(av0.y, w1, acc0);
      acc0 = fmaf(av0.z, w2, acc0); acc0 = fmaf(av0.w, w3, acc0);
      acc1 = fmaf(av1.x, w0, acc1); acc1 = fmaf(av1.y, w1, acc1);
      acc1 = fmaf(av1.z, w2, acc1); acc1 = fmaf(av1.w, w3, acc1);
      acc2 = fmaf(av2.x, w0, acc2); acc2 = fmaf(av2.y, w1, acc2);
      acc2 = fmaf(av2.z, w2, acc2); acc2 = fmaf(av2.w, w3, acc2);
      acc3 = fmaf(av3.x, w0, acc3); acc3 = fmaf(av3.y, w1, acc3);
      acc3 = fmaf(av3.z, w2, acc3); acc3 = fmaf(av3.w, w3, acc3);
    }
    __syncthreads();  // all agg reads complete before buf is repurposed
    buf[w][0][lane] = acc0;  // p layout [head][node][c]
    buf[w][1][lane] = acc1;
    buf[w][2][lane] = acc2;
    buf[w][3][lane] = acc3;
    __syncthreads();
    if (n < N) {
      out[(size_t)n * 64 + lane] = buf[0][w][lane] + buf[1][w][lane] +
                                   buf[2][w][lane] + buf[3][w][lane] + bv;
    }
  }
}

extern "C" void kernel_launch(void* const* d_in, const int* in_sizes, int n_in,
                              void* d_out, int out_size, void* d_ws, size_t ws_size,
                              hipStream_t stream) {
  const float* meta_x = (const float*)d_in[0];
  const int* ei = (const int*)d_in[1];  // int32 edge index [2,E] flat
  const float* W = (const float*)d_in[2];
  const float* att_src = (const float*)d_in[3];
  const float* att_dst = (const float*)d_in[4];
  const float* bias = (const float*)d_in[5];
  float* out = (float*)d_out;

  int N = in_sizes[0] / 64;
  int E = in_sizes[1] / 2;
  int ET = E + N;

  char* ws = (char*)d_ws;
  size_t off = 0;
  auto alloc = [&](size_t bytes) {
    size_t o = off;
    off += (bytes + 255) & ~(size_t)255;
    return o;
  };
  size_t o_wsrc = alloc(64 * 4 * sizeof(float));
  size_t o_wdst = alloc(64 * 4 * sizeof(float));
  size_t o_asrc = alloc((size_t)N * 4 * sizeof(float));
  size_t o_adst = alloc((size_t)N * 4 * sizeof(float));
  size_t o_cnt = alloc((size_t)N * sizeof(int));
  size_t o_row = alloc(((size_t)N + 1) * sizeof(int));
  size_t o_cur = alloc((size_t)N * sizeof(int));
  size_t o_srt = alloc((size_t)ET * sizeof(int));
  size_t o_ts = alloc((((size_t)N + 255) / 256) * sizeof(int));
  (void)ws_size;  // ~5.6 MB total

  float* wsrc = (float*)(ws + o_wsrc);
  float* wdst = (float*)(ws + o_wdst);
  float4* asrc4 = (float4*)(ws + o_asrc);
  float4* adst4 = (float4*)(ws + o_adst);
  int* cnt = (int*)(ws + o_cnt);
  int* row = (int*)(ws + o_row);
  int* cur = (int*)(ws + o_cur);
  int* srt = (int*)(ws + o_srt);
  int* tsum = (int*)(ws + o_ts);

  hipMemsetAsync(cnt, 0, (size_t)N * sizeof(int), stream);

  patt_kernel<<<1, 256, 0, stream>>>(W, att_src, att_dst, wsrc, wdst);
  nattn_kernel<<<(N + 3) / 4, 256, 0, stream>>>(meta_x, (const float4*)wsrc,
                                                (const float4*)wdst, asrc4, adst4, N);
  hist_kernel<<<(ET + 255) / 256, 256, 0, stream>>>(ei, cnt, E, N);
  int ntiles = (N + 255) / 256;
  scanA_kernel<<<ntiles, 256, 0, stream>>>(cnt, tsum, N);
  scanB_kernel<<<1, 256, 0, stream>>>(tsum, ntiles);
  scanC_kernel<<<ntiles, 256, 0, stream>>>(cnt, tsum, row, cur, N);
  scatter_kernel<<<(ET + 255) / 256, 256, 0, stream>>>(ei, cur, srt, E, N);
  int ngroups = (N + 3) / 4;
  int ggrid = ngroups < 1792 ? ngroups : 1792;  // 256 CU x 7 blocks/CU (VGPR-capped)
  gatout_kernel<<<ggrid, 256, 0, stream>>>(srt, row, asrc4, adst4, meta_x, W, bias, out, N);
}

// Round 7
// 217.084 us; speedup vs baseline: 2.0193x; 1.0323x over previous
//
#include <hip/hip_runtime.h>
#include <math.h>

#define MAXDEG 64

__device__ __forceinline__ float lrelu(float v) { return v > 0.0f ? v : 0.2f * v; }

// ---- Kernel A: fold attention vectors into W: wsrc[k,h] = sum_c W[k,h*64+c]*att_src[h,c]
__global__ void patt_kernel(const float* __restrict__ W, const float* __restrict__ att_src,
                            const float* __restrict__ att_dst, float* __restrict__ wsrc,
                            float* __restrict__ wdst) {
  int t = threadIdx.x;  // 256 threads: h = t>>6, k = t&63
  int h = t >> 6, k = t & 63;
  const float* wrow = W + (size_t)k * 256 + h * 64;
  const float* as = att_src + h * 64;
  const float* ad = att_dst + h * 64;
  float ss = 0.f, sd = 0.f;
#pragma unroll
  for (int c = 0; c < 64; ++c) {
    float w = wrow[c];
    ss = fmaf(w, as[c], ss);
    sd = fmaf(w, ad[c], sd);
  }
  wsrc[k * 4 + h] = ss;
  wdst[k * 4 + h] = sd;
}

// ---- Kernel B: per-node attention scalars a_src/a_dst = meta_x @ wsrc/wdst  -> [N,4]
__global__ void nattn_kernel(const float* __restrict__ x, const float4* __restrict__ wsrc4,
                             const float4* __restrict__ wdst4, float4* __restrict__ asrc4,
                             float4* __restrict__ adst4, int N) {
  int lane = threadIdx.x & 63;
  int n = blockIdx.x * 4 + (threadIdx.x >> 6);
  if (n >= N) return;
  float xv = x[(size_t)n * 64 + lane];
  float4 ws = wsrc4[lane], wd = wdst4[lane];
  float s0 = xv * ws.x, s1 = xv * ws.y, s2 = xv * ws.z, s3 = xv * ws.w;
  float d0 = xv * wd.x, d1 = xv * wd.y, d2 = xv * wd.z, d3 = xv * wd.w;
#pragma unroll
  for (int m = 1; m < 64; m <<= 1) {
    s0 += __shfl_xor(s0, m, 64); s1 += __shfl_xor(s1, m, 64);
    s2 += __shfl_xor(s2, m, 64); s3 += __shfl_xor(s3, m, 64);
    d0 += __shfl_xor(d0, m, 64); d1 += __shfl_xor(d1, m, 64);
    d2 += __shfl_xor(d2, m, 64); d3 += __shfl_xor(d3, m, 64);
  }
  if (lane == 0) {
    asrc4[n] = make_float4(s0, s1, s2, s3);
    adst4[n] = make_float4(d0, d1, d2, d3);
  }
}

// ---- Kernel C: histogram of destinations (self-loops appended at the end) [proven]
__global__ void hist_kernel(const int* __restrict__ ei, int* __restrict__ counts,
                            int E, int N) {
  int e = blockIdx.x * 256 + threadIdx.x;
  int ET = E + N;
  if (e >= ET) return;
  int dst = (e < E) ? ei[(size_t)E + e] : (e - E);
  atomicAdd(&counts[dst], 1);
}

// ---- Hierarchical scan, phase A: per-tile (256 counts) sums. Coalesced. [proven r5]
__global__ void scanA_kernel(const int* __restrict__ cnt, int* __restrict__ tsum, int N) {
  int b = blockIdx.x, t = threadIdx.x;
  int idx = b * 256 + t;
  int v = (idx < N) ? cnt[idx] : 0;
#pragma unroll
  for (int m = 1; m < 64; m <<= 1) v += __shfl_xor(v, m, 64);
  __shared__ int ws[4];
  if ((t & 63) == 0) ws[t >> 6] = v;
  __syncthreads();
  if (t == 0) tsum[b] = ws[0] + ws[1] + ws[2] + ws[3];
}

// ---- Phase B: exclusive scan of tile sums [proven r5]
__global__ void scanB_kernel(int* __restrict__ tsum, int ntiles) {
  __shared__ int part[256];
  int t = threadIdx.x;
  int carry = 0;
  for (int b0 = 0; b0 < ntiles; b0 += 256) {
    int idx = b0 + t;
    int v = (idx < ntiles) ? tsum[idx] : 0;
    part[t] = v;
    __syncthreads();
    for (int d = 1; d < 256; d <<= 1) {
      int u = (t >= d) ? part[t - d] : 0;
      __syncthreads();
      part[t] += u;
      __syncthreads();
    }
    if (idx < ntiles) tsum[idx] = part[t] - v + carry;  // exclusive + carry
    carry += part[255];
    __syncthreads();
  }
}

// ---- Phase C: intra-tile exclusive scan + tile offset -> row_start, cursor [proven r5]
__global__ void scanC_kernel(const int* __restrict__ cnt, const int* __restrict__ tsum,
                             int* __restrict__ row, int* __restrict__ cur, int N) {
  __shared__ int part[256];
  int b = blockIdx.x, t = threadIdx.x;
  int idx = b * 256 + t;
  int c = (idx < N) ? cnt[idx] : 0;
  part[t] = c;
  __syncthreads();
  for (int d = 1; d < 256; d <<= 1) {
    int u = (t >= d) ? part[t - d] : 0;
    __syncthreads();
    part[t] += u;
    __syncthreads();
  }
  int exc = part[t] - c + tsum[b];
  if (idx < N) {
    row[idx] = exc;
    cur[idx] = exc;
    if (idx == N - 1) row[N] = exc + c;
  }
}

// ---- Kernel E: scatter edge sources into dst-sorted order [proven]
__global__ void scatter_kernel(const int* __restrict__ ei, int* __restrict__ cursor,
                               int* __restrict__ src_sorted, int E, int N) {
  int e = blockIdx.x * 256 + threadIdx.x;
  int ET = E + N;
  if (e >= ET) return;
  int src, dst;
  if (e < E) {
    src = ei[e];
    dst = ei[(size_t)E + e];
  } else {
    src = dst = e - E;
  }
  int pos = atomicAdd(&cursor[dst], 1);
  src_sorted[pos] = src;
}

// ---- Fused: per-node softmax + aggregation + projection.
// LDS = 5120 B: buf ALIASES alL (never cross-wave live at once; wave w's agg
// writes land exactly in its own alL quarter). One extra loop-top barrier
// protects next iteration's alL writes vs other waves' final buf reads.
__global__ __launch_bounds__(256) void gatout_kernel(
    const int* __restrict__ srt, const int* __restrict__ row,
    const float4* __restrict__ asrc4, const float4* __restrict__ adst4,
    const float* __restrict__ x, const float* __restrict__ W,
    const float* __restrict__ bias, float* __restrict__ out, int N) {
  __shared__ float4 smem4[320];                                  // 5120 B total
  float4 (*alL)[MAXDEG] = (float4(*)[MAXDEG])smem4;              // [4][64] @ 0 (4096B)
  int (*slL)[MAXDEG] = (int(*)[MAXDEG])(smem4 + 256);            // [4][64] @ 4096 (1024B)
  float (*buf)[4][64] = (float(*)[4][64])smem4;                  // [4][4][64] @ 0 (alias)
  int t = threadIdx.x, w = t >> 6, lane = t & 63;
  float Wreg[64];  // W[k, w*64 + lane]
#pragma unroll
  for (int k = 0; k < 64; ++k) Wreg[k] = W[(size_t)k * 256 + w * 64 + lane];
  float bv = bias[lane];
  int ngroups = (N + 3) >> 2;
  for (int g = blockIdx.x; g < ngroups; g += gridDim.x) {
    int n = g * 4 + w;
    float a0 = 0.f, a1 = 0.f, a2 = 0.f, a3 = 0.f;
    float r0 = 0.f, r1 = 0.f, r2 = 0.f, r3 = 0.f;
    __syncthreads();  // prev iteration's buf reads done before alL (alias) writes
    if (n < N) {
      int start = row[n], end = row[n + 1];
      int deg = end - start;
      float4 ad = adst4[n];
      float t0 = 0.f, t1 = 0.f, t2 = 0.f, t3 = 0.f;
      if (deg <= MAXDEG) {
        // Pass A: compute exp(logit), cache in own wave's LDS quarter, accumulate sums
        for (int b = 0; b < deg; b += 64) {
          if (b + lane < deg) {
            int sl = srt[start + b + lane];
            float4 as = asrc4[sl];
            float4 e;
            e.x = __expf(lrelu(as.x + ad.x));
            e.y = __expf(lrelu(as.y + ad.y));
            e.z = __expf(lrelu(as.z + ad.z));
            e.w = __expf(lrelu(as.w + ad.w));
            alL[w][b + lane] = e;
            slL[w][b + lane] = sl;
            t0 += e.x; t1 += e.y; t2 += e.z; t3 += e.w;
          }
        }
      } else {
        for (int b = start; b < end; b += 64) {
          int idx = b + lane;
          if (idx < end) {
            int sl = srt[idx];
            float4 as = asrc4[sl];
            t0 += __expf(lrelu(as.x + ad.x));
            t1 += __expf(lrelu(as.y + ad.y));
            t2 += __expf(lrelu(as.z + ad.z));
            t3 += __expf(lrelu(as.w + ad.w));
          }
        }
      }
      // butterfly sum (adds only — no exps)
#pragma unroll
      for (int m = 1; m < 64; m <<= 1) {
        t0 += __shfl_xor(t0, m, 64);
        t1 += __shfl_xor(t1, m, 64);
        t2 += __shfl_xor(t2, m, 64);
        t3 += __shfl_xor(t3, m, 64);
      }
      r0 = 0.25f / (t0 + 1e-16f); r1 = 0.25f / (t1 + 1e-16f);
      r2 = 0.25f / (t2 + 1e-16f); r3 = 0.25f / (t3 + 1e-16f);
      // Pass B: weighted aggregation (lane = channel), alphas replayed from LDS
      if (deg <= MAXDEG) {
        int j = 0;
        for (; j + 4 <= deg; j += 4) {
          float4 e0 = alL[w][j], e1 = alL[w][j + 1], e2 = alL[w][j + 2], e3 = alL[w][j + 3];
          int q0 = slL[w][j], q1 = slL[w][j + 1], q2 = slL[w][j + 2], q3 = slL[w][j + 3];
          float v0 = x[(size_t)q0 * 64 + lane];
          float v1 = x[(size_t)q1 * 64 + lane];
          float v2 = x[(size_t)q2 * 64 + lane];
          float v3 = x[(size_t)q3 * 64 + lane];
          a0 = fmaf(e0.x, v0, a0); a1 = fmaf(e0.y, v0, a1);
          a2 = fmaf(e0.z, v0, a2); a3 = fmaf(e0.w, v0, a3);
          a0 = fmaf(e1.x, v1, a0); a1 = fmaf(e1.y, v1, a1);
          a2 = fmaf(e1.z, v1, a2); a3 = fmaf(e1.w, v1, a3);
          a0 = fmaf(e2.x, v2, a0); a1 = fmaf(e2.y, v2, a1);
          a2 = fmaf(e2.z, v2, a2); a3 = fmaf(e2.w, v2, a3);
          a0 = fmaf(e3.x, v3, a0); a1 = fmaf(e3.y, v3, a1);
          a2 = fmaf(e3.z, v3, a2); a3 = fmaf(e3.w, v3, a3);
        }
        for (; j < deg; ++j) {
          float4 e0 = alL[w][j];
          int q0 = slL[w][j];
          float v0 = x[(size_t)q0 * 64 + lane];
          a0 = fmaf(e0.x, v0, a0); a1 = fmaf(e0.y, v0, a1);
          a2 = fmaf(e0.z, v0, a2); a3 = fmaf(e0.w, v0, a3);
        }
      } else {
        for (int b = start; b < end; b += 64) {
          int cnt = end - b;
          if (cnt > 64) cnt = 64;
          int idx = b + lane;
          int sl = 0;
          float e0 = 0.f, e1 = 0.f, e2 = 0.f, e3 = 0.f;
          if (idx < end) {
            sl = srt[idx];
            float4 as = asrc4[sl];
            e0 = __expf(lrelu(as.x + ad.x));
            e1 = __expf(lrelu(as.y + ad.y));
            e2 = __expf(lrelu(as.z + ad.z));
            e3 = __expf(lrelu(as.w + ad.w));
          }
          for (int j = 0; j < cnt; ++j) {
            int sj = __shfl(sl, j, 64);
            float b0 = __shfl(e0, j, 64), b1 = __shfl(e1, j, 64);
            float b2 = __shfl(e2, j, 64), b3 = __shfl(e3, j, 64);
            float v = x[(size_t)sj * 64 + lane];
            a0 = fmaf(b0, v, a0); a1 = fmaf(b1, v, a1);
            a2 = fmaf(b2, v, a2); a3 = fmaf(b3, v, a3);
          }
        }
      }
    }
    __syncthreads();  // all alL reads (own-wave) + prior buf lifetime closed
    buf[w][0][lane] = a0 * r0;   // agg layout [node][head][k] — wave w's own quarter
    buf[w][1][lane] = a1 * r1;
    buf[w][2][lane] = a2 * r2;
    buf[w][3][lane] = a3 * r3;
    __syncthreads();
    // Phase 2: wave w = head w. acc[i] = sum_k agg[i][w][k] * W[k, w*64+c] (registers)
    float acc0 = 0.f, acc1 = 0.f, acc2 = 0.f, acc3 = 0.f;
#pragma unroll
    for (int k4 = 0; k4 < 16; ++k4) {
      float4 av0 = *(const float4*)&buf[0][w][k4 * 4];
      float4 av1 = *(const float4*)&buf[1][w][k4 * 4];
      float4 av2 = *(const float4*)&buf[2][w][k4 * 4];
      float4 av3 = *(const float4*)&buf[3][w][k4 * 4];
      float w0 = Wreg[k4 * 4 + 0], w1 = Wreg[k4 * 4 + 1];
      float w2 = Wreg[k4 * 4 + 2], w3 = Wreg[k4 * 4 + 3];
      acc0 = fmaf(av0.x, w0, acc0); acc0 = fmaf(av0.y, w1, acc0);
      acc0 = fmaf(av0.z, w2, acc0); acc0 = fmaf(av0.w, w3, acc0);
      acc1 = fmaf(av1.x, w0, acc1); acc1 = fmaf(av1.y, w1, acc1);
      acc1 = fmaf(av1.z, w2, acc1); acc1 = fmaf(av1.w, w3, acc1);
      acc2 = fmaf(av2.x, w0, acc2); acc2 = fmaf(av2.y, w1, acc2);
      acc2 = fmaf(av2.z, w2, acc2); acc2 = fmaf(av2.w, w3, acc2);
      acc3 = fmaf(av3.x, w0, acc3); acc3 = fmaf(av3.y, w1, acc3);
      acc3 = fmaf(av3.z, w2, acc3); acc3 = fmaf(av3.w, w3, acc3);
    }
    __syncthreads();  // all agg reads complete before buf is repurposed
    buf[w][0][lane] = acc0;  // p layout [head][node][c] — own quarter again
    buf[w][1][lane] = acc1;
    buf[w][2][lane] = acc2;
    buf[w][3][lane] = acc3;
    __syncthreads();
    if (n < N) {
      out[(size_t)n * 64 + lane] = buf[0][w][lane] + buf[1][w][lane] +
                                   buf[2][w][lane] + buf[3][w][lane] + bv;
    }
  }
}

extern "C" void kernel_launch(void* const* d_in, const int* in_sizes, int n_in,
                              void* d_out, int out_size, void* d_ws, size_t ws_size,
                              hipStream_t stream) {
  const float* meta_x = (const float*)d_in[0];
  const int* ei = (const int*)d_in[1];  // int32 edge index [2,E] flat
  const float* W = (const float*)d_in[2];
  const float* att_src = (const float*)d_in[3];
  const float* att_dst = (const float*)d_in[4];
  const float* bias = (const float*)d_in[5];
  float* out = (float*)d_out;

  int N = in_sizes[0] / 64;
  int E = in_sizes[1] / 2;
  int ET = E + N;

  char* ws = (char*)d_ws;
  size_t off = 0;
  auto alloc = [&](size_t bytes) {
    size_t o = off;
    off += (bytes + 255) & ~(size_t)255;
    return o;
  };
  size_t o_wsrc = alloc(64 * 4 * sizeof(float));
  size_t o_wdst = alloc(64 * 4 * sizeof(float));
  size_t o_asrc = alloc((size_t)N * 4 * sizeof(float));
  size_t o_adst = alloc((size_t)N * 4 * sizeof(float));
  size_t o_cnt = alloc((size_t)N * sizeof(int));
  size_t o_row = alloc(((size_t)N + 1) * sizeof(int));
  size_t o_cur = alloc((size_t)N * sizeof(int));
  size_t o_srt = alloc((size_t)ET * sizeof(int));
  size_t o_ts = alloc((((size_t)N + 255) / 256) * sizeof(int));
  (void)ws_size;  // ~5.6 MB total

  float* wsrc = (float*)(ws + o_wsrc);
  float* wdst = (float*)(ws + o_wdst);
  float4* asrc4 = (float4*)(ws + o_asrc);
  float4* adst4 = (float4*)(ws + o_adst);
  int* cnt = (int*)(ws + o_cnt);
  int* row = (int*)(ws + o_row);
  int* cur = (int*)(ws + o_cur);
  int* srt = (int*)(ws + o_srt);
  int* tsum = (int*)(ws + o_ts);

  hipMemsetAsync(cnt, 0, (size_t)N * sizeof(int), stream);

  patt_kernel<<<1, 256, 0, stream>>>(W, att_src, att_dst, wsrc, wdst);
  nattn_kernel<<<(N + 3) / 4, 256, 0, stream>>>(meta_x, (const float4*)wsrc,
                                                (const float4*)wdst, asrc4, adst4, N);
  hist_kernel<<<(ET + 255) / 256, 256, 0, stream>>>(ei, cnt, E, N);
  int ntiles = (N + 255) / 256;
  scanA_kernel<<<ntiles, 256, 0, stream>>>(cnt, tsum, N);
  scanB_kernel<<<1, 256, 0, stream>>>(tsum, ntiles);
  scanC_kernel<<<ntiles, 256, 0, stream>>>(cnt, tsum, row, cur, N);
  scatter_kernel<<<(ET + 255) / 256, 256, 0, stream>>>(ei, cur, srt, E, N);
  int ngroups = (N + 3) / 4;
  int ggrid = ngroups < 2048 ? ngroups : 2048;  // up to 8 blocks/CU
  gatout_kernel<<<ggrid, 256, 0, stream>>>(srt, row, asrc4, adst4, meta_x, W, bias, out, N);
}

// Round 8
// 209.374 us; speedup vs baseline: 2.0937x; 1.0368x over previous
//
#include <hip/hip_runtime.h>
#include <math.h>

#define MAXDEG 64

__device__ __forceinline__ float lrelu(float v) { return v > 0.0f ? v : 0.2f * v; }

// ---- Kernel A: fold attention vectors into W: wsrc[k,h] = sum_c W[k,h*64+c]*att_src[h,c]
__global__ void patt_kernel(const float* __restrict__ W, const float* __restrict__ att_src,
                            const float* __restrict__ att_dst, float* __restrict__ wsrc,
                            float* __restrict__ wdst) {
  int t = threadIdx.x;  // 256 threads: h = t>>6, k = t&63
  int h = t >> 6, k = t & 63;
  const float* wrow = W + (size_t)k * 256 + h * 64;
  const float* as = att_src + h * 64;
  const float* ad = att_dst + h * 64;
  float ss = 0.f, sd = 0.f;
#pragma unroll
  for (int c = 0; c < 64; ++c) {
    float w = wrow[c];
    ss = fmaf(w, as[c], ss);
    sd = fmaf(w, ad[c], sd);
  }
  wsrc[k * 4 + h] = ss;
  wdst[k * 4 + h] = sd;
}

// ---- Kernel B: per-node attention scalars a_src/a_dst = meta_x @ wsrc/wdst  -> [N,4]
__global__ void nattn_kernel(const float* __restrict__ x, const float4* __restrict__ wsrc4,
                             const float4* __restrict__ wdst4, float4* __restrict__ asrc4,
                             float4* __restrict__ adst4, int N) {
  int lane = threadIdx.x & 63;
  int n = blockIdx.x * 4 + (threadIdx.x >> 6);
  if (n >= N) return;
  float xv = x[(size_t)n * 64 + lane];
  float4 ws = wsrc4[lane], wd = wdst4[lane];
  float s0 = xv * ws.x, s1 = xv * ws.y, s2 = xv * ws.z, s3 = xv * ws.w;
  float d0 = xv * wd.x, d1 = xv * wd.y, d2 = xv * wd.z, d3 = xv * wd.w;
#pragma unroll
  for (int m = 1; m < 64; m <<= 1) {
    s0 += __shfl_xor(s0, m, 64); s1 += __shfl_xor(s1, m, 64);
    s2 += __shfl_xor(s2, m, 64); s3 += __shfl_xor(s3, m, 64);
    d0 += __shfl_xor(d0, m, 64); d1 += __shfl_xor(d1, m, 64);
    d2 += __shfl_xor(d2, m, 64); d3 += __shfl_xor(d3, m, 64);
  }
  if (lane == 0) {
    asrc4[n] = make_float4(s0, s1, s2, s3);
    adst4[n] = make_float4(d0, d1, d2, d3);
  }
}

// ---- Scalar hist/scatter [round-2 proven, fallback when E%4 != 0]
__global__ void hist_kernel(const int* __restrict__ ei, int* __restrict__ counts,
                            int E, int N) {
  int e = blockIdx.x * 256 + threadIdx.x;
  int ET = E + N;
  if (e >= ET) return;
  int dst = (e < E) ? ei[(size_t)E + e] : (e - E);
  atomicAdd(&counts[dst], 1);
}

__global__ void scatter_kernel(const int* __restrict__ ei, int* __restrict__ cursor,
                               int* __restrict__ src_sorted, int E, int N) {
  int e = blockIdx.x * 256 + threadIdx.x;
  int ET = E + N;
  if (e >= ET) return;
  int src, dst;
  if (e < E) {
    src = ei[e];
    dst = ei[(size_t)E + e];
  } else {
    src = dst = e - E;
  }
  int pos = atomicAdd(&cursor[dst], 1);
  src_sorted[pos] = src;
}

// ---- int4 hist/scatter (E%4==0 path): threads [0,E4) take 4 real edges,
// [E4, E4+N) take self-loop for node i-E4. Same CSR semantics as scalar.
__global__ void hist4_kernel(const int* __restrict__ ei, int* __restrict__ counts,
                             int E, int N) {
  int i = blockIdx.x * 256 + threadIdx.x;
  int E4 = E >> 2;
  if (i < E4) {
    int4 d = ((const int4*)(ei + E))[i];
    atomicAdd(&counts[d.x], 1);
    atomicAdd(&counts[d.y], 1);
    atomicAdd(&counts[d.z], 1);
    atomicAdd(&counts[d.w], 1);
  } else if (i < E4 + N) {
    atomicAdd(&counts[i - E4], 1);
  }
}

__global__ void scatter4_kernel(const int* __restrict__ ei, int* __restrict__ cursor,
                                int* __restrict__ srt, int E, int N) {
  int i = blockIdx.x * 256 + threadIdx.x;
  int E4 = E >> 2;
  if (i < E4) {
    int4 s4 = ((const int4*)ei)[i];
    int4 d4 = ((const int4*)(ei + E))[i];
    int p;
    p = atomicAdd(&cursor[d4.x], 1); srt[p] = s4.x;
    p = atomicAdd(&cursor[d4.y], 1); srt[p] = s4.y;
    p = atomicAdd(&cursor[d4.z], 1); srt[p] = s4.z;
    p = atomicAdd(&cursor[d4.w], 1); srt[p] = s4.w;
  } else if (i < E4 + N) {
    int node = i - E4;
    int p = atomicAdd(&cursor[node], 1);
    srt[p] = node;
  }
}

// ---- Hierarchical scan [proven r5]
__global__ void scanA_kernel(const int* __restrict__ cnt, int* __restrict__ tsum, int N) {
  int b = blockIdx.x, t = threadIdx.x;
  int idx = b * 256 + t;
  int v = (idx < N) ? cnt[idx] : 0;
#pragma unroll
  for (int m = 1; m < 64; m <<= 1) v += __shfl_xor(v, m, 64);
  __shared__ int ws[4];
  if ((t & 63) == 0) ws[t >> 6] = v;
  __syncthreads();
  if (t == 0) tsum[b] = ws[0] + ws[1] + ws[2] + ws[3];
}

__global__ void scanB_kernel(int* __restrict__ tsum, int ntiles) {
  __shared__ int part[256];
  int t = threadIdx.x;
  int carry = 0;
  for (int b0 = 0; b0 < ntiles; b0 += 256) {
    int idx = b0 + t;
    int v = (idx < ntiles) ? tsum[idx] : 0;
    part[t] = v;
    __syncthreads();
    for (int d = 1; d < 256; d <<= 1) {
      int u = (t >= d) ? part[t - d] : 0;
      __syncthreads();
      part[t] += u;
      __syncthreads();
    }
    if (idx < ntiles) tsum[idx] = part[t] - v + carry;  // exclusive + carry
    carry += part[255];
    __syncthreads();
  }
}

__global__ void scanC_kernel(const int* __restrict__ cnt, const int* __restrict__ tsum,
                             int* __restrict__ row, int* __restrict__ cur, int N) {
  __shared__ int part[256];
  int b = blockIdx.x, t = threadIdx.x;
  int idx = b * 256 + t;
  int c = (idx < N) ? cnt[idx] : 0;
  part[t] = c;
  __syncthreads();
  for (int d = 1; d < 256; d <<= 1) {
    int u = (t >= d) ? part[t - d] : 0;
    __syncthreads();
    part[t] += u;
    __syncthreads();
  }
  int exc = part[t] - c + tsum[b];
  if (idx < N) {
    row[idx] = exc;
    cur[idx] = exc;
    if (idx == N - 1) row[N] = exc + c;
  }
}

// ---- Aggregation kernel: one wave per node, ZERO barriers (waves independent;
// per-wave LDS cache; a wave is internally synchronous). Writes agg[N][256].
__global__ __launch_bounds__(256) void agg_kernel(
    const int* __restrict__ srt, const int* __restrict__ row,
    const float4* __restrict__ asrc4, const float4* __restrict__ adst4,
    const float* __restrict__ x, float* __restrict__ agg, int N) {
  __shared__ float4 alL[4][MAXDEG];  // 4096B
  __shared__ int slL[4][MAXDEG];     // 1024B
  int t = threadIdx.x, w = t >> 6, lane = t & 63;
  int n = blockIdx.x * 4 + w;
  if (n >= N) return;
  int start = row[n], end = row[n + 1];
  int deg = end - start;
  float4 ad = adst4[n];
  float t0 = 0.f, t1 = 0.f, t2 = 0.f, t3 = 0.f;
  if (deg <= MAXDEG) {
    for (int b = 0; b < deg; b += 64) {
      if (b + lane < deg) {
        int sl = srt[start + b + lane];
        float4 as = asrc4[sl];
        float4 e;
        e.x = __expf(lrelu(as.x + ad.x));
        e.y = __expf(lrelu(as.y + ad.y));
        e.z = __expf(lrelu(as.z + ad.z));
        e.w = __expf(lrelu(as.w + ad.w));
        alL[w][b + lane] = e;
        slL[w][b + lane] = sl;
        t0 += e.x; t1 += e.y; t2 += e.z; t3 += e.w;
      }
    }
  } else {
    for (int b = start; b < end; b += 64) {
      int idx = b + lane;
      if (idx < end) {
        int sl = srt[idx];
        float4 as = asrc4[sl];
        t0 += __expf(lrelu(as.x + ad.x));
        t1 += __expf(lrelu(as.y + ad.y));
        t2 += __expf(lrelu(as.z + ad.z));
        t3 += __expf(lrelu(as.w + ad.w));
      }
    }
  }
#pragma unroll
  for (int m = 1; m < 64; m <<= 1) {
    t0 += __shfl_xor(t0, m, 64);
    t1 += __shfl_xor(t1, m, 64);
    t2 += __shfl_xor(t2, m, 64);
    t3 += __shfl_xor(t3, m, 64);
  }
  float r0 = 0.25f / (t0 + 1e-16f), r1 = 0.25f / (t1 + 1e-16f);
  float r2 = 0.25f / (t2 + 1e-16f), r3 = 0.25f / (t3 + 1e-16f);
  float a0 = 0.f, a1 = 0.f, a2 = 0.f, a3 = 0.f;
  if (deg <= MAXDEG) {
    int j = 0;
    for (; j + 4 <= deg; j += 4) {
      float4 e0 = alL[w][j], e1 = alL[w][j + 1], e2 = alL[w][j + 2], e3 = alL[w][j + 3];
      int q0 = slL[w][j], q1 = slL[w][j + 1], q2 = slL[w][j + 2], q3 = slL[w][j + 3];
      float v0 = x[(size_t)q0 * 64 + lane];
      float v1 = x[(size_t)q1 * 64 + lane];
      float v2 = x[(size_t)q2 * 64 + lane];
      float v3 = x[(size_t)q3 * 64 + lane];
      a0 = fmaf(e0.x, v0, a0); a1 = fmaf(e0.y, v0, a1);
      a2 = fmaf(e0.z, v0, a2); a3 = fmaf(e0.w, v0, a3);
      a0 = fmaf(e1.x, v1, a0); a1 = fmaf(e1.y, v1, a1);
      a2 = fmaf(e1.z, v1, a2); a3 = fmaf(e1.w, v1, a3);
      a0 = fmaf(e2.x, v2, a0); a1 = fmaf(e2.y, v2, a1);
      a2 = fmaf(e2.z, v2, a2); a3 = fmaf(e2.w, v2, a3);
      a0 = fmaf(e3.x, v3, a0); a1 = fmaf(e3.y, v3, a1);
      a2 = fmaf(e3.z, v3, a2); a3 = fmaf(e3.w, v3, a3);
    }
    for (; j < deg; ++j) {
      float4 e0 = alL[w][j];
      int q0 = slL[w][j];
      float v0 = x[(size_t)q0 * 64 + lane];
      a0 = fmaf(e0.x, v0, a0); a1 = fmaf(e0.y, v0, a1);
      a2 = fmaf(e0.z, v0, a2); a3 = fmaf(e0.w, v0, a3);
    }
  } else {
    for (int b = start; b < end; b += 64) {
      int cnt = end - b;
      if (cnt > 64) cnt = 64;
      int idx = b + lane;
      int sl = 0;
      float e0 = 0.f, e1 = 0.f, e2 = 0.f, e3 = 0.f;
      if (idx < end) {
        sl = srt[idx];
        float4 as = asrc4[sl];
        e0 = __expf(lrelu(as.x + ad.x));
        e1 = __expf(lrelu(as.y + ad.y));
        e2 = __expf(lrelu(as.z + ad.z));
        e3 = __expf(lrelu(as.w + ad.w));
      }
      for (int j = 0; j < cnt; ++j) {
        int sj = __shfl(sl, j, 64);
        float b0 = __shfl(e0, j, 64), b1 = __shfl(e1, j, 64);
        float b2 = __shfl(e2, j, 64), b3 = __shfl(e3, j, 64);
        float v = x[(size_t)sj * 64 + lane];
        a0 = fmaf(b0, v, a0); a1 = fmaf(b1, v, a1);
        a2 = fmaf(b2, v, a2); a3 = fmaf(b3, v, a3);
      }
    }
  }
  float* ao = agg + (size_t)n * 256;
  ao[lane] = a0 * r0;
  ao[64 + lane] = a1 * r1;
  ao[128 + lane] = a2 * r2;
  ao[192 + lane] = a3 * r3;
}

// ---- Projection: out[n][c] = sum_h sum_k agg[n][h*64+k] W[k][h*64+c] + bias[c]
// Regular mini-GEMM; r6-proven phase-2 arithmetic, agg staged via LDS.
__global__ __launch_bounds__(256) void proj_kernel(
    const float* __restrict__ agg, const float* __restrict__ W,
    const float* __restrict__ bias, float* __restrict__ out, int N) {
  __shared__ float aggL[4][256];   // 4KB
  __shared__ float pL[4][4][64];   // 4KB
  int t = threadIdx.x, w = t >> 6, lane = t & 63;
  float Wreg[64];  // W[k, w*64 + lane]
#pragma unroll
  for (int k = 0; k < 64; ++k) Wreg[k] = W[(size_t)k * 256 + w * 64 + lane];
  float bv = bias[lane];
  int ngroups = (N + 3) >> 2;
  for (int g = blockIdx.x; g < ngroups; g += gridDim.x) {
    int n0 = g * 4;
    __syncthreads();  // prev iteration's pL reads / aggL reads done
    {                 // stage agg[4 nodes][256]: thread t loads one float4
      int nn = n0 + w;
      if (nn < N)
        *(float4*)&aggL[w][(t & 63) * 4] =
            *(const float4*)&agg[(size_t)nn * 256 + (t & 63) * 4];
      else
        *(float4*)&aggL[w][(t & 63) * 4] = make_float4(0.f, 0.f, 0.f, 0.f);
    }
    __syncthreads();
    float acc0 = 0.f, acc1 = 0.f, acc2 = 0.f, acc3 = 0.f;
#pragma unroll
    for (int k4 = 0; k4 < 16; ++k4) {
      float4 av0 = *(const float4*)&aggL[0][w * 64 + k4 * 4];
      float4 av1 = *(const float4*)&aggL[1][w * 64 + k4 * 4];
      float4 av2 = *(const float4*)&aggL[2][w * 64 + k4 * 4];
      float4 av3 = *(const float4*)&aggL[3][w * 64 + k4 * 4];
      float w0 = Wreg[k4 * 4 + 0], w1 = Wreg[k4 * 4 + 1];
      float w2 = Wreg[k4 * 4 + 2], w3 = Wreg[k4 * 4 + 3];
      acc0 = fmaf(av0.x, w0, acc0); acc0 = fmaf(av0.y, w1, acc0);
      acc0 = fmaf(av0.z, w2, acc0); acc0 = fmaf(av0.w, w3, acc0);
      acc1 = fmaf(av1.x, w0, acc1); acc1 = fmaf(av1.y, w1, acc1);
      acc1 = fmaf(av1.z, w2, acc1); acc1 = fmaf(av1.w, w3, acc1);
      acc2 = fmaf(av2.x, w0, acc2); acc2 = fmaf(av2.y, w1, acc2);
      acc2 = fmaf(av2.z, w2, acc2); acc2 = fmaf(av2.w, w3, acc2);
      acc3 = fmaf(av3.x, w0, acc3); acc3 = fmaf(av3.y, w1, acc3);
      acc3 = fmaf(av3.z, w2, acc3); acc3 = fmaf(av3.w, w3, acc3);
    }
    pL[w][0][lane] = acc0;  // p[head w][node i][c]
    pL[w][1][lane] = acc1;
    pL[w][2][lane] = acc2;
    pL[w][3][lane] = acc3;
    __syncthreads();
    int nn = n0 + w;
    if (nn < N) {
      out[(size_t)nn * 64 + lane] = pL[0][w][lane] + pL[1][w][lane] +
                                    pL[2][w][lane] + pL[3][w][lane] + bv;
    }
  }
}

// ---- Fused fallback (r6-proven) used only if ws_size can't hold the agg buffer.
__global__ __launch_bounds__(256) void gatout_kernel(
    const int* __restrict__ srt, const int* __restrict__ row,
    const float4* __restrict__ asrc4, const float4* __restrict__ adst4,
    const float* __restrict__ x, const float* __restrict__ W,
    const float* __restrict__ bias, float* __restrict__ out, int N) {
  __shared__ float4 smem4[320];
  float4 (*alL)[MAXDEG] = (float4(*)[MAXDEG])smem4;
  int (*slL)[MAXDEG] = (int(*)[MAXDEG])(smem4 + 256);
  float (*buf)[4][64] = (float(*)[4][64])smem4;
  int t = threadIdx.x, w = t >> 6, lane = t & 63;
  float Wreg[64];
#pragma unroll
  for (int k = 0; k < 64; ++k) Wreg[k] = W[(size_t)k * 256 + w * 64 + lane];
  float bv = bias[lane];
  int ngroups = (N + 3) >> 2;
  for (int g = blockIdx.x; g < ngroups; g += gridDim.x) {
    int n = g * 4 + w;
    float a0 = 0.f, a1 = 0.f, a2 = 0.f, a3 = 0.f;
    float r0 = 0.f, r1 = 0.f, r2 = 0.f, r3 = 0.f;
    __syncthreads();
    if (n < N) {
      int start = row[n], end = row[n + 1];
      int deg = end - start;
      float4 ad = adst4[n];
      float t0 = 0.f, t1 = 0.f, t2 = 0.f, t3 = 0.f;
      if (deg <= MAXDEG) {
        for (int b = 0; b < deg; b += 64) {
          if (b + lane < deg) {
            int sl = srt[start + b + lane];
            float4 as = asrc4[sl];
            float4 e;
            e.x = __expf(lrelu(as.x + ad.x));
            e.y = __expf(lrelu(as.y + ad.y));
            e.z = __expf(lrelu(as.z + ad.z));
            e.w = __expf(lrelu(as.w + ad.w));
            alL[w][b + lane] = e;
            slL[w][b + lane] = sl;
            t0 += e.x; t1 += e.y; t2 += e.z; t3 += e.w;
          }
        }
      } else {
        for (int b = start; b < end; b += 64) {
          int idx = b + lane;
          if (idx < end) {
            int sl = srt[idx];
            float4 as = asrc4[sl];
            t0 += __expf(lrelu(as.x + ad.x));
            t1 += __expf(lrelu(as.y + ad.y));
            t2 += __expf(lrelu(as.z + ad.z));
            t3 += __expf(lrelu(as.w + ad.w));
          }
        }
      }
#pragma unroll
      for (int m = 1; m < 64; m <<= 1) {
        t0 += __shfl_xor(t0, m, 64);
        t1 += __shfl_xor(t1, m, 64);
        t2 += __shfl_xor(t2, m, 64);
        t3 += __shfl_xor(t3, m, 64);
      }
      r0 = 0.25f / (t0 + 1e-16f); r1 = 0.25f / (t1 + 1e-16f);
      r2 = 0.25f / (t2 + 1e-16f); r3 = 0.25f / (t3 + 1e-16f);
      if (deg <= MAXDEG) {
        int j = 0;
        for (; j + 4 <= deg; j += 4) {
          float4 e0 = alL[w][j], e1 = alL[w][j + 1], e2 = alL[w][j + 2], e3 = alL[w][j + 3];
          int q0 = slL[w][j], q1 = slL[w][j + 1], q2 = slL[w][j + 2], q3 = slL[w][j + 3];
          float v0 = x[(size_t)q0 * 64 + lane];
          float v1 = x[(size_t)q1 * 64 + lane];
          float v2 = x[(size_t)q2 * 64 + lane];
          float v3 = x[(size_t)q3 * 64 + lane];
          a0 = fmaf(e0.x, v0, a0); a1 = fmaf(e0.y, v0, a1);
          a2 = fmaf(e0.z, v0, a2); a3 = fmaf(e0.w, v0, a3);
          a0 = fmaf(e1.x, v1, a0); a1 = fmaf(e1.y, v1, a1);
          a2 = fmaf(e1.z, v1, a2); a3 = fmaf(e1.w, v1, a3);
          a0 = fmaf(e2.x, v2, a0); a1 = fmaf(e2.y, v2, a1);
          a2 = fmaf(e2.z, v2, a2); a3 = fmaf(e2.w, v2, a3);
          a0 = fmaf(e3.x, v3, a0); a1 = fmaf(e3.y, v3, a1);
          a2 = fmaf(e3.z, v3, a2); a3 = fmaf(e3.w, v3, a3);
        }
        for (; j < deg; ++j) {
          float4 e0 = alL[w][j];
          int q0 = slL[w][j];
          float v0 = x[(size_t)q0 * 64 + lane];
          a0 = fmaf(e0.x, v0, a0); a1 = fmaf(e0.y, v0, a1);
          a2 = fmaf(e0.z, v0, a2); a3 = fmaf(e0.w, v0, a3);
        }
      } else {
        for (int b = start; b < end; b += 64) {
          int cnt = end - b;
          if (cnt > 64) cnt = 64;
          int idx = b + lane;
          int sl = 0;
          float e0 = 0.f, e1 = 0.f, e2 = 0.f, e3 = 0.f;
          if (idx < end) {
            sl = srt[idx];
            float4 as = asrc4[sl];
            e0 = __expf(lrelu(as.x + ad.x));
            e1 = __expf(lrelu(as.y + ad.y));
            e2 = __expf(lrelu(as.z + ad.z));
            e3 = __expf(lrelu(as.w + ad.w));
          }
          for (int j = 0; j < cnt; ++j) {
            int sj = __shfl(sl, j, 64);
            float b0 = __shfl(e0, j, 64), b1 = __shfl(e1, j, 64);
            float b2 = __shfl(e2, j, 64), b3 = __shfl(e3, j, 64);
            float v = x[(size_t)sj * 64 + lane];
            a0 = fmaf(b0, v, a0); a1 = fmaf(b1, v, a1);
            a2 = fmaf(b2, v, a2); a3 = fmaf(b3, v, a3);
          }
        }
      }
    }
    __syncthreads();
    buf[w][0][lane] = a0 * r0;
    buf[w][1][lane] = a1 * r1;
    buf[w][2][lane] = a2 * r2;
    buf[w][3][lane] = a3 * r3;
    __syncthreads();
    float acc0 = 0.f, acc1 = 0.f, acc2 = 0.f, acc3 = 0.f;
#pragma unroll
    for (int k4 = 0; k4 < 16; ++k4) {
      float4 av0 = *(const float4*)&buf[0][w][k4 * 4];
      float4 av1 = *(const float4*)&buf[1][w][k4 * 4];
      float4 av2 = *(const float4*)&buf[2][w][k4 * 4];
      float4 av3 = *(const float4*)&buf[3][w][k4 * 4];
      float w0 = Wreg[k4 * 4 + 0], w1 = Wreg[k4 * 4 + 1];
      float w2 = Wreg[k4 * 4 + 2], w3 = Wreg[k4 * 4 + 3];
      acc0 = fmaf(av0.x, w0, acc0); acc0 = fmaf(av0.y, w1, acc0);
      acc0 = fmaf(av0.z, w2, acc0); acc0 = fmaf(av0.w, w3, acc0);
      acc1 = fmaf(av1.x, w0, acc1); acc1 = fmaf(av1.y, w1, acc1);
      acc1 = fmaf(av1.z, w2, acc1); acc1 = fmaf(av1.w, w3, acc1);
      acc2 = fmaf(av2.x, w0, acc2); acc2 = fmaf(av2.y, w1, acc2);
      acc2 = fmaf(av2.z, w2, acc2); acc2 = fmaf(av2.w, w3, acc2);
      acc3 = fmaf(av3.x, w0, acc3); acc3 = fmaf(av3.y, w1, acc3);
      acc3 = fmaf(av3.z, w2, acc3); acc3 = fmaf(av3.w, w3, acc3);
    }
    __syncthreads();
    buf[w][0][lane] = acc0;
    buf[w][1][lane] = acc1;
    buf[w][2][lane] = acc2;
    buf[w][3][lane] = acc3;
    __syncthreads();
    if (n < N) {
      out[(size_t)n * 64 + lane] = buf[0][w][lane] + buf[1][w][lane] +
                                   buf[2][w][lane] + buf[3][w][lane] + bv;
    }
  }
}

extern "C" void kernel_launch(void* const* d_in, const int* in_sizes, int n_in,
                              void* d_out, int out_size, void* d_ws, size_t ws_size,
                              hipStream_t stream) {
  const float* meta_x = (const float*)d_in[0];
  const int* ei = (const int*)d_in[1];  // int32 edge index [2,E] flat
  const float* W = (const float*)d_in[2];
  const float* att_src = (const float*)d_in[3];
  const float* att_dst = (const float*)d_in[4];
  const float* bias = (const float*)d_in[5];
  float* out = (float*)d_out;

  int N = in_sizes[0] / 64;
  int E = in_sizes[1] / 2;
  int ET = E + N;

  char* ws = (char*)d_ws;
  size_t off = 0;
  auto alloc = [&](size_t bytes) {
    size_t o = off;
    off += (bytes + 255) & ~(size_t)255;
    return o;
  };
  size_t o_wsrc = alloc(64 * 4 * sizeof(float));
  size_t o_wdst = alloc(64 * 4 * sizeof(float));
  size_t o_asrc = alloc((size_t)N * 4 * sizeof(float));
  size_t o_adst = alloc((size_t)N * 4 * sizeof(float));
  size_t o_cnt = alloc((size_t)N * sizeof(int));
  size_t o_row = alloc(((size_t)N + 1) * sizeof(int));
  size_t o_cur = alloc((size_t)N * sizeof(int));
  size_t o_srt = alloc((size_t)ET * sizeof(int));
  size_t o_ts = alloc((((size_t)N + 255) / 256) * sizeof(int));
  size_t base_sz = off;
  size_t o_agg = alloc((size_t)N * 256 * sizeof(float));  // 51.2 MB
  bool split = (ws_size >= off);
  (void)base_sz;

  float* wsrc = (float*)(ws + o_wsrc);
  float* wdst = (float*)(ws + o_wdst);
  float4* asrc4 = (float4*)(ws + o_asrc);
  float4* adst4 = (float4*)(ws + o_adst);
  int* cnt = (int*)(ws + o_cnt);
  int* row = (int*)(ws + o_row);
  int* cur = (int*)(ws + o_cur);
  int* srt = (int*)(ws + o_srt);
  int* tsum = (int*)(ws + o_ts);
  float* aggp = (float*)(ws + o_agg);

  hipMemsetAsync(cnt, 0, (size_t)N * sizeof(int), stream);

  patt_kernel<<<1, 256, 0, stream>>>(W, att_src, att_dst, wsrc, wdst);
  nattn_kernel<<<(N + 3) / 4, 256, 0, stream>>>(meta_x, (const float4*)wsrc,
                                                (const float4*)wdst, asrc4, adst4, N);
  if ((E & 3) == 0) {
    int nt4 = (E >> 2) + N;
    hist4_kernel<<<(nt4 + 255) / 256, 256, 0, stream>>>(ei, cnt, E, N);
  } else {
    hist_kernel<<<(ET + 255) / 256, 256, 0, stream>>>(ei, cnt, E, N);
  }
  int ntiles = (N + 255) / 256;
  scanA_kernel<<<ntiles, 256, 0, stream>>>(cnt, tsum, N);
  scanB_kernel<<<1, 256, 0, stream>>>(tsum, ntiles);
  scanC_kernel<<<ntiles, 256, 0, stream>>>(cnt, tsum, row, cur, N);
  if ((E & 3) == 0) {
    int nt4 = (E >> 2) + N;
    scatter4_kernel<<<(nt4 + 255) / 256, 256, 0, stream>>>(ei, cur, srt, E, N);
  } else {
    scatter_kernel<<<(ET + 255) / 256, 256, 0, stream>>>(ei, cur, srt, E, N);
  }
  if (split) {
    agg_kernel<<<(N + 3) / 4, 256, 0, stream>>>(srt, row, asrc4, adst4, meta_x, aggp, N);
    int ngroups = (N + 3) / 4;
    int pgrid = ngroups < 2048 ? ngroups : 2048;
    proj_kernel<<<pgrid, 256, 0, stream>>>(aggp, W, bias, out, N);
  } else {
    int ngroups = (N + 3) / 4;
    int ggrid = ngroups < 2048 ? ngroups : 2048;
    gatout_kernel<<<ggrid, 256, 0, stream>>>(srt, row, asrc4, adst4, meta_x, W, bias, out, N);
  }
}

// Round 9
// 197.091 us; speedup vs baseline: 2.2242x; 1.0623x over previous
//
#include <hip/hip_runtime.h>
#include <math.h>

#define MAXDEG 64

__device__ __forceinline__ float lrelu(float v) { return v > 0.0f ? v : 0.2f * v; }

// ---- Kernel A: fold attention vectors into W: wsrc[k,h] = sum_c W[k,h*64+c]*att_src[h,c]
__global__ void patt_kernel(const float* __restrict__ W, const float* __restrict__ att_src,
                            const float* __restrict__ att_dst, float* __restrict__ wsrc,
                            float* __restrict__ wdst) {
  int t = threadIdx.x;  // 256 threads: h = t>>6, k = t&63
  int h = t >> 6, k = t & 63;
  const float* wrow = W + (size_t)k * 256 + h * 64;
  const float* as = att_src + h * 64;
  const float* ad = att_dst + h * 64;
  float ss = 0.f, sd = 0.f;
#pragma unroll
  for (int c = 0; c < 64; ++c) {
    float w = wrow[c];
    ss = fmaf(w, as[c], ss);
    sd = fmaf(w, ad[c], sd);
  }
  wsrc[k * 4 + h] = ss;
  wdst[k * 4 + h] = sd;
}

// ---- Kernel B: per-node attention scalars a_src/a_dst = meta_x @ wsrc/wdst  -> [N,4]
__global__ void nattn_kernel(const float* __restrict__ x, const float4* __restrict__ wsrc4,
                             const float4* __restrict__ wdst4, float4* __restrict__ asrc4,
                             float4* __restrict__ adst4, int N) {
  int lane = threadIdx.x & 63;
  int n = blockIdx.x * 4 + (threadIdx.x >> 6);
  if (n >= N) return;
  float xv = x[(size_t)n * 64 + lane];
  float4 ws = wsrc4[lane], wd = wdst4[lane];
  float s0 = xv * ws.x, s1 = xv * ws.y, s2 = xv * ws.z, s3 = xv * ws.w;
  float d0 = xv * wd.x, d1 = xv * wd.y, d2 = xv * wd.z, d3 = xv * wd.w;
#pragma unroll
  for (int m = 1; m < 64; m <<= 1) {
    s0 += __shfl_xor(s0, m, 64); s1 += __shfl_xor(s1, m, 64);
    s2 += __shfl_xor(s2, m, 64); s3 += __shfl_xor(s3, m, 64);
    d0 += __shfl_xor(d0, m, 64); d1 += __shfl_xor(d1, m, 64);
    d2 += __shfl_xor(d2, m, 64); d3 += __shfl_xor(d3, m, 64);
  }
  if (lane == 0) {
    asrc4[n] = make_float4(s0, s1, s2, s3);
    adst4[n] = make_float4(d0, d1, d2, d3);
  }
}

// ---- Scalar hist/scatter [round-2 proven, fallback when E%4 != 0]
__global__ void hist_kernel(const int* __restrict__ ei, int* __restrict__ counts,
                            int E, int N) {
  int e = blockIdx.x * 256 + threadIdx.x;
  int ET = E + N;
  if (e >= ET) return;
  int dst = (e < E) ? ei[(size_t)E + e] : (e - E);
  atomicAdd(&counts[dst], 1);
}

__global__ void scatter_kernel(const int* __restrict__ ei, int* __restrict__ cursor,
                               int* __restrict__ src_sorted, int E, int N) {
  int e = blockIdx.x * 256 + threadIdx.x;
  int ET = E + N;
  if (e >= ET) return;
  int src, dst;
  if (e < E) {
    src = ei[e];
    dst = ei[(size_t)E + e];
  } else {
    src = dst = e - E;
  }
  int pos = atomicAdd(&cursor[dst], 1);
  src_sorted[pos] = src;
}

// ---- int4 hist (E%4==0 path) [proven r8]
__global__ void hist4_kernel(const int* __restrict__ ei, int* __restrict__ counts,
                             int E, int N) {
  int i = blockIdx.x * 256 + threadIdx.x;
  int E4 = E >> 2;
  if (i < E4) {
    int4 d = ((const int4*)(ei + E))[i];
    atomicAdd(&counts[d.x], 1);
    atomicAdd(&counts[d.y], 1);
    atomicAdd(&counts[d.z], 1);
    atomicAdd(&counts[d.w], 1);
  } else if (i < E4 + N) {
    atomicAdd(&counts[i - E4], 1);
  }
}

// ---- XCD-sliced scatter (E%4==0 path): dst-space split into 8 slices; block b
// owns slice b&7 (same blockIdx%8 -> same XCD under round-robin dispatch). Each
// slice's blocks grid-stride the whole edge list, committing only their slice's
// edges -> each srt region written by ONE XCD -> lines coalesce in its L2.
__global__ void scatter8_kernel(const int* __restrict__ ei, int* __restrict__ cursor,
                                int* __restrict__ srt, int E, int N) {
  int slice = blockIdx.x & 7;
  int bid = blockIdx.x >> 3;
  int nb = gridDim.x >> 3;
  int chunk = (N + 7) >> 3;
  int lo = slice * chunk;
  int hi = lo + chunk; if (hi > N) hi = N;
  int E4 = E >> 2;
  const int4* s4p = (const int4*)ei;
  const int4* d4p = (const int4*)(ei + E);
  int stride = nb * 256;
  for (int i = bid * 256 + threadIdx.x; i < E4; i += stride) {
    int4 d4 = d4p[i];
    bool bx = (d4.x >= lo && d4.x < hi), by = (d4.y >= lo && d4.y < hi);
    bool bz = (d4.z >= lo && d4.z < hi), bw = (d4.w >= lo && d4.w < hi);
    if (!(bx || by || bz || bw)) continue;
    int4 s4 = s4p[i];
    if (bx) { int p = atomicAdd(&cursor[d4.x], 1); srt[p] = s4.x; }
    if (by) { int p = atomicAdd(&cursor[d4.y], 1); srt[p] = s4.y; }
    if (bz) { int p = atomicAdd(&cursor[d4.z], 1); srt[p] = s4.z; }
    if (bw) { int p = atomicAdd(&cursor[d4.w], 1); srt[p] = s4.w; }
  }
  // self-loops for this slice's nodes
  for (int n = lo + bid * 256 + threadIdx.x; n < hi; n += stride) {
    int p = atomicAdd(&cursor[n], 1);
    srt[p] = n;
  }
}

// ---- Hierarchical scan [proven r5]
__global__ void scanA_kernel(const int* __restrict__ cnt, int* __restrict__ tsum, int N) {
  int b = blockIdx.x, t = threadIdx.x;
  int idx = b * 256 + t;
  int v = (idx < N) ? cnt[idx] : 0;
#pragma unroll
  for (int m = 1; m < 64; m <<= 1) v += __shfl_xor(v, m, 64);
  __shared__ int ws[4];
  if ((t & 63) == 0) ws[t >> 6] = v;
  __syncthreads();
  if (t == 0) tsum[b] = ws[0] + ws[1] + ws[2] + ws[3];
}

__global__ void scanB_kernel(int* __restrict__ tsum, int ntiles) {
  __shared__ int part[256];
  int t = threadIdx.x;
  int carry = 0;
  for (int b0 = 0; b0 < ntiles; b0 += 256) {
    int idx = b0 + t;
    int v = (idx < ntiles) ? tsum[idx] : 0;
    part[t] = v;
    __syncthreads();
    for (int d = 1; d < 256; d <<= 1) {
      int u = (t >= d) ? part[t - d] : 0;
      __syncthreads();
      part[t] += u;
      __syncthreads();
    }
    if (idx < ntiles) tsum[idx] = part[t] - v + carry;  // exclusive + carry
    carry += part[255];
    __syncthreads();
  }
}

__global__ void scanC_kernel(const int* __restrict__ cnt, const int* __restrict__ tsum,
                             int* __restrict__ row, int* __restrict__ cur, int N) {
  __shared__ int part[256];
  int b = blockIdx.x, t = threadIdx.x;
  int idx = b * 256 + t;
  int c = (idx < N) ? cnt[idx] : 0;
  part[t] = c;
  __syncthreads();
  for (int d = 1; d < 256; d <<= 1) {
    int u = (t >= d) ? part[t - d] : 0;
    __syncthreads();
    part[t] += u;
    __syncthreads();
  }
  int exc = part[t] - c + tsum[b];
  if (idx < N) {
    row[idx] = exc;
    cur[idx] = exc;
    if (idx == N - 1) row[N] = exc + c;
  }
}

// ---- Aggregation kernel: one wave per node, ZERO barriers [proven r8]
__global__ __launch_bounds__(256) void agg_kernel(
    const int* __restrict__ srt, const int* __restrict__ row,
    const float4* __restrict__ asrc4, const float4* __restrict__ adst4,
    const float* __restrict__ x, float* __restrict__ agg, int N) {
  __shared__ float4 alL[4][MAXDEG];  // 4096B
  __shared__ int slL[4][MAXDEG];     // 1024B
  int t = threadIdx.x, w = t >> 6, lane = t & 63;
  int n = blockIdx.x * 4 + w;
  if (n >= N) return;
  int start = row[n], end = row[n + 1];
  int deg = end - start;
  float4 ad = adst4[n];
  float t0 = 0.f, t1 = 0.f, t2 = 0.f, t3 = 0.f;
  if (deg <= MAXDEG) {
    for (int b = 0; b < deg; b += 64) {
      if (b + lane < deg) {
        int sl = srt[start + b + lane];
        float4 as = asrc4[sl];
        float4 e;
        e.x = __expf(lrelu(as.x + ad.x));
        e.y = __expf(lrelu(as.y + ad.y));
        e.z = __expf(lrelu(as.z + ad.z));
        e.w = __expf(lrelu(as.w + ad.w));
        alL[w][b + lane] = e;
        slL[w][b + lane] = sl;
        t0 += e.x; t1 += e.y; t2 += e.z; t3 += e.w;
      }
    }
  } else {
    for (int b = start; b < end; b += 64) {
      int idx = b + lane;
      if (idx < end) {
        int sl = srt[idx];
        float4 as = asrc4[sl];
        t0 += __expf(lrelu(as.x + ad.x));
        t1 += __expf(lrelu(as.y + ad.y));
        t2 += __expf(lrelu(as.z + ad.z));
        t3 += __expf(lrelu(as.w + ad.w));
      }
    }
  }
#pragma unroll
  for (int m = 1; m < 64; m <<= 1) {
    t0 += __shfl_xor(t0, m, 64);
    t1 += __shfl_xor(t1, m, 64);
    t2 += __shfl_xor(t2, m, 64);
    t3 += __shfl_xor(t3, m, 64);
  }
  float r0 = 0.25f / (t0 + 1e-16f), r1 = 0.25f / (t1 + 1e-16f);
  float r2 = 0.25f / (t2 + 1e-16f), r3 = 0.25f / (t3 + 1e-16f);
  float a0 = 0.f, a1 = 0.f, a2 = 0.f, a3 = 0.f;
  if (deg <= MAXDEG) {
    int j = 0;
    for (; j + 4 <= deg; j += 4) {
      float4 e0 = alL[w][j], e1 = alL[w][j + 1], e2 = alL[w][j + 2], e3 = alL[w][j + 3];
      int q0 = slL[w][j], q1 = slL[w][j + 1], q2 = slL[w][j + 2], q3 = slL[w][j + 3];
      float v0 = x[(size_t)q0 * 64 + lane];
      float v1 = x[(size_t)q1 * 64 + lane];
      float v2 = x[(size_t)q2 * 64 + lane];
      float v3 = x[(size_t)q3 * 64 + lane];
      a0 = fmaf(e0.x, v0, a0); a1 = fmaf(e0.y, v0, a1);
      a2 = fmaf(e0.z, v0, a2); a3 = fmaf(e0.w, v0, a3);
      a0 = fmaf(e1.x, v1, a0); a1 = fmaf(e1.y, v1, a1);
      a2 = fmaf(e1.z, v1, a2); a3 = fmaf(e1.w, v1, a3);
      a0 = fmaf(e2.x, v2, a0); a1 = fmaf(e2.y, v2, a1);
      a2 = fmaf(e2.z, v2, a2); a3 = fmaf(e2.w, v2, a3);
      a0 = fmaf(e3.x, v3, a0); a1 = fmaf(e3.y, v3, a1);
      a2 = fmaf(e3.z, v3, a2); a3 = fmaf(e3.w, v3, a3);
    }
    for (; j < deg; ++j) {
      float4 e0 = alL[w][j];
      int q0 = slL[w][j];
      float v0 = x[(size_t)q0 * 64 + lane];
      a0 = fmaf(e0.x, v0, a0); a1 = fmaf(e0.y, v0, a1);
      a2 = fmaf(e0.z, v0, a2); a3 = fmaf(e0.w, v0, a3);
    }
  } else {
    for (int b = start; b < end; b += 64) {
      int cnt = end - b;
      if (cnt > 64) cnt = 64;
      int idx = b + lane;
      int sl = 0;
      float e0 = 0.f, e1 = 0.f, e2 = 0.f, e3 = 0.f;
      if (idx < end) {
        sl = srt[idx];
        float4 as = asrc4[sl];
        e0 = __expf(lrelu(as.x + ad.x));
        e1 = __expf(lrelu(as.y + ad.y));
        e2 = __expf(lrelu(as.z + ad.z));
        e3 = __expf(lrelu(as.w + ad.w));
      }
      for (int j = 0; j < cnt; ++j) {
        int sj = __shfl(sl, j, 64);
        float b0 = __shfl(e0, j, 64), b1 = __shfl(e1, j, 64);
        float b2 = __shfl(e2, j, 64), b3 = __shfl(e3, j, 64);
        float v = x[(size_t)sj * 64 + lane];
        a0 = fmaf(b0, v, a0); a1 = fmaf(b1, v, a1);
        a2 = fmaf(b2, v, a2); a3 = fmaf(b3, v, a3);
      }
    }
  }
  float* ao = agg + (size_t)n * 256;
  ao[lane] = a0 * r0;
  ao[64 + lane] = a1 * r1;
  ao[128 + lane] = a2 * r2;
  ao[192 + lane] = a3 * r3;
}

// ---- Projection [proven r8]
__global__ __launch_bounds__(256) void proj_kernel(
    const float* __restrict__ agg, const float* __restrict__ W,
    const float* __restrict__ bias, float* __restrict__ out, int N) {
  __shared__ float aggL[4][256];   // 4KB
  __shared__ float pL[4][4][64];   // 4KB
  int t = threadIdx.x, w = t >> 6, lane = t & 63;
  float Wreg[64];  // W[k, w*64 + lane]
#pragma unroll
  for (int k = 0; k < 64; ++k) Wreg[k] = W[(size_t)k * 256 + w * 64 + lane];
  float bv = bias[lane];
  int ngroups = (N + 3) >> 2;
  for (int g = blockIdx.x; g < ngroups; g += gridDim.x) {
    int n0 = g * 4;
    __syncthreads();  // prev iteration's pL reads / aggL reads done
    {
      int nn = n0 + w;
      if (nn < N)
        *(float4*)&aggL[w][(t & 63) * 4] =
            *(const float4*)&agg[(size_t)nn * 256 + (t & 63) * 4];
      else
        *(float4*)&aggL[w][(t & 63) * 4] = make_float4(0.f, 0.f, 0.f, 0.f);
    }
    __syncthreads();
    float acc0 = 0.f, acc1 = 0.f, acc2 = 0.f, acc3 = 0.f;
#pragma unroll
    for (int k4 = 0; k4 < 16; ++k4) {
      float4 av0 = *(const float4*)&aggL[0][w * 64 + k4 * 4];
      float4 av1 = *(const float4*)&aggL[1][w * 64 + k4 * 4];
      float4 av2 = *(const float4*)&aggL[2][w * 64 + k4 * 4];
      float4 av3 = *(const float4*)&aggL[3][w * 64 + k4 * 4];
      float w0 = Wreg[k4 * 4 + 0], w1 = Wreg[k4 * 4 + 1];
      float w2 = Wreg[k4 * 4 + 2], w3 = Wreg[k4 * 4 + 3];
      acc0 = fmaf(av0.x, w0, acc0); acc0 = fmaf(av0.y, w1, acc0);
      acc0 = fmaf(av0.z, w2, acc0); acc0 = fmaf(av0.w, w3, acc0);
      acc1 = fmaf(av1.x, w0, acc1); acc1 = fmaf(av1.y, w1, acc1);
      acc1 = fmaf(av1.z, w2, acc1); acc1 = fmaf(av1.w, w3, acc1);
      acc2 = fmaf(av2.x, w0, acc2); acc2 = fmaf(av2.y, w1, acc2);
      acc2 = fmaf(av2.z, w2, acc2); acc2 = fmaf(av2.w, w3, acc2);
      acc3 = fmaf(av3.x, w0, acc3); acc3 = fmaf(av3.y, w1, acc3);
      acc3 = fmaf(av3.z, w2, acc3); acc3 = fmaf(av3.w, w3, acc3);
    }
    pL[w][0][lane] = acc0;
    pL[w][1][lane] = acc1;
    pL[w][2][lane] = acc2;
    pL[w][3][lane] = acc3;
    __syncthreads();
    int nn = n0 + w;
    if (nn < N) {
      out[(size_t)nn * 64 + lane] = pL[0][w][lane] + pL[1][w][lane] +
                                    pL[2][w][lane] + pL[3][w][lane] + bv;
    }
  }
}

// ---- Fused fallback (r6-proven) used only if ws_size can't hold the agg buffer.
__global__ __launch_bounds__(256) void gatout_kernel(
    const int* __restrict__ srt, const int* __restrict__ row,
    const float4* __restrict__ asrc4, const float4* __restrict__ adst4,
    const float* __restrict__ x, const float* __restrict__ W,
    const float* __restrict__ bias, float* __restrict__ out, int N) {
  __shared__ float4 smem4[320];
  float4 (*alL)[MAXDEG] = (float4(*)[MAXDEG])smem4;
  int (*slL)[MAXDEG] = (int(*)[MAXDEG])(smem4 + 256);
  float (*buf)[4][64] = (float(*)[4][64])smem4;
  int t = threadIdx.x, w = t >> 6, lane = t & 63;
  float Wreg[64];
#pragma unroll
  for (int k = 0; k < 64; ++k) Wreg[k] = W[(size_t)k * 256 + w * 64 + lane];
  float bv = bias[lane];
  int ngroups = (N + 3) >> 2;
  for (int g = blockIdx.x; g < ngroups; g += gridDim.x) {
    int n = g * 4 + w;
    float a0 = 0.f, a1 = 0.f, a2 = 0.f, a3 = 0.f;
    float r0 = 0.f, r1 = 0.f, r2 = 0.f, r3 = 0.f;
    __syncthreads();
    if (n < N) {
      int start = row[n], end = row[n + 1];
      int deg = end - start;
      float4 ad = adst4[n];
      float t0 = 0.f, t1 = 0.f, t2 = 0.f, t3 = 0.f;
      if (deg <= MAXDEG) {
        for (int b = 0; b < deg; b += 64) {
          if (b + lane < deg) {
            int sl = srt[start + b + lane];
            float4 as = asrc4[sl];
            float4 e;
            e.x = __expf(lrelu(as.x + ad.x));
            e.y = __expf(lrelu(as.y + ad.y));
            e.z = __expf(lrelu(as.z + ad.z));
            e.w = __expf(lrelu(as.w + ad.w));
            alL[w][b + lane] = e;
            slL[w][b + lane] = sl;
            t0 += e.x; t1 += e.y; t2 += e.z; t3 += e.w;
          }
        }
      } else {
        for (int b = start; b < end; b += 64) {
          int idx = b + lane;
          if (idx < end) {
            int sl = srt[idx];
            float4 as = asrc4[sl];
            t0 += __expf(lrelu(as.x + ad.x));
            t1 += __expf(lrelu(as.y + ad.y));
            t2 += __expf(lrelu(as.z + ad.z));
            t3 += __expf(lrelu(as.w + ad.w));
          }
        }
      }
#pragma unroll
      for (int m = 1; m < 64; m <<= 1) {
        t0 += __shfl_xor(t0, m, 64);
        t1 += __shfl_xor(t1, m, 64);
        t2 += __shfl_xor(t2, m, 64);
        t3 += __shfl_xor(t3, m, 64);
      }
      r0 = 0.25f / (t0 + 1e-16f); r1 = 0.25f / (t1 + 1e-16f);
      r2 = 0.25f / (t2 + 1e-16f); r3 = 0.25f / (t3 + 1e-16f);
      if (deg <= MAXDEG) {
        int j = 0;
        for (; j + 4 <= deg; j += 4) {
          float4 e0 = alL[w][j], e1 = alL[w][j + 1], e2 = alL[w][j + 2], e3 = alL[w][j + 3];
          int q0 = slL[w][j], q1 = slL[w][j + 1], q2 = slL[w][j + 2], q3 = slL[w][j + 3];
          float v0 = x[(size_t)q0 * 64 + lane];
          float v1 = x[(size_t)q1 * 64 + lane];
          float v2 = x[(size_t)q2 * 64 + lane];
          float v3 = x[(size_t)q3 * 64 + lane];
          a0 = fmaf(e0.x, v0, a0); a1 = fmaf(e0.y, v0, a1);
          a2 = fmaf(e0.z, v0, a2); a3 = fmaf(e0.w, v0, a3);
          a0 = fmaf(e1.x, v1, a0); a1 = fmaf(e1.y, v1, a1);
          a2 = fmaf(e1.z, v1, a2); a3 = fmaf(e1.w, v1, a3);
          a0 = fmaf(e2.x, v2, a0); a1 = fmaf(e2.y, v2, a1);
          a2 = fmaf(e2.z, v2, a2); a3 = fmaf(e2.w, v2, a3);
          a0 = fmaf(e3.x, v3, a0); a1 = fmaf(e3.y, v3, a1);
          a2 = fmaf(e3.z, v3, a2); a3 = fmaf(e3.w, v3, a3);
        }
        for (; j < deg; ++j) {
          float4 e0 = alL[w][j];
          int q0 = slL[w][j];
          float v0 = x[(size_t)q0 * 64 + lane];
          a0 = fmaf(e0.x, v0, a0); a1 = fmaf(e0.y, v0, a1);
          a2 = fmaf(e0.z, v0, a2); a3 = fmaf(e0.w, v0, a3);
        }
      } else {
        for (int b = start; b < end; b += 64) {
          int cnt = end - b;
          if (cnt > 64) cnt = 64;
          int idx = b + lane;
          int sl = 0;
          float e0 = 0.f, e1 = 0.f, e2 = 0.f, e3 = 0.f;
          if (idx < end) {
            sl = srt[idx];
            float4 as = asrc4[sl];
            e0 = __expf(lrelu(as.x + ad.x));
            e1 = __expf(lrelu(as.y + ad.y));
            e2 = __expf(lrelu(as.z + ad.z));
            e3 = __expf(lrelu(as.w + ad.w));
          }
          for (int j = 0; j < cnt; ++j) {
            int sj = __shfl(sl, j, 64);
            float b0 = __shfl(e0, j, 64), b1 = __shfl(e1, j, 64);
            float b2 = __shfl(e2, j, 64), b3 = __shfl(e3, j, 64);
            float v = x[(size_t)sj * 64 + lane];
            a0 = fmaf(b0, v, a0); a1 = fmaf(b1, v, a1);
            a2 = fmaf(b2, v, a2); a3 = fmaf(b3, v, a3);
          }
        }
      }
    }
    __syncthreads();
    buf[w][0][lane] = a0 * r0;
    buf[w][1][lane] = a1 * r1;
    buf[w][2][lane] = a2 * r2;
    buf[w][3][lane] = a3 * r3;
    __syncthreads();
    float acc0 = 0.f, acc1 = 0.f, acc2 = 0.f, acc3 = 0.f;
#pragma unroll
    for (int k4 = 0; k4 < 16; ++k4) {
      float4 av0 = *(const float4*)&buf[0][w][k4 * 4];
      float4 av1 = *(const float4*)&buf[1][w][k4 * 4];
      float4 av2 = *(const float4*)&buf[2][w][k4 * 4];
      float4 av3 = *(const float4*)&buf[3][w][k4 * 4];
      float w0 = Wreg[k4 * 4 + 0], w1 = Wreg[k4 * 4 + 1];
      float w2 = Wreg[k4 * 4 + 2], w3 = Wreg[k4 * 4 + 3];
      acc0 = fmaf(av0.x, w0, acc0); acc0 = fmaf(av0.y, w1, acc0);
      acc0 = fmaf(av0.z, w2, acc0); acc0 = fmaf(av0.w, w3, acc0);
      acc1 = fmaf(av1.x, w0, acc1); acc1 = fmaf(av1.y, w1, acc1);
      acc1 = fmaf(av1.z, w2, acc1); acc1 = fmaf(av1.w, w3, acc1);
      acc2 = fmaf(av2.x, w0, acc2); acc2 = fmaf(av2.y, w1, acc2);
      acc2 = fmaf(av2.z, w2, acc2); acc2 = fmaf(av2.w, w3, acc2);
      acc3 = fmaf(av3.x, w0, acc3); acc3 = fmaf(av3.y, w1, acc3);
      acc3 = fmaf(av3.z, w2, acc3); acc3 = fmaf(av3.w, w3, acc3);
    }
    __syncthreads();
    buf[w][0][lane] = acc0;
    buf[w][1][lane] = acc1;
    buf[w][2][lane] = acc2;
    buf[w][3][lane] = acc3;
    __syncthreads();
    if (n < N) {
      out[(size_t)n * 64 + lane] = buf[0][w][lane] + buf[1][w][lane] +
                                   buf[2][w][lane] + buf[3][w][lane] + bv;
    }
  }
}

extern "C" void kernel_launch(void* const* d_in, const int* in_sizes, int n_in,
                              void* d_out, int out_size, void* d_ws, size_t ws_size,
                              hipStream_t stream) {
  const float* meta_x = (const float*)d_in[0];
  const int* ei = (const int*)d_in[1];  // int32 edge index [2,E] flat
  const float* W = (const float*)d_in[2];
  const float* att_src = (const float*)d_in[3];
  const float* att_dst = (const float*)d_in[4];
  const float* bias = (const float*)d_in[5];
  float* out = (float*)d_out;

  int N = in_sizes[0] / 64;
  int E = in_sizes[1] / 2;
  int ET = E + N;

  char* ws = (char*)d_ws;
  size_t off = 0;
  auto alloc = [&](size_t bytes) {
    size_t o = off;
    off += (bytes + 255) & ~(size_t)255;
    return o;
  };
  size_t o_wsrc = alloc(64 * 4 * sizeof(float));
  size_t o_wdst = alloc(64 * 4 * sizeof(float));
  size_t o_asrc = alloc((size_t)N * 4 * sizeof(float));
  size_t o_adst = alloc((size_t)N * 4 * sizeof(float));
  size_t o_cnt = alloc((size_t)N * sizeof(int));
  size_t o_row = alloc(((size_t)N + 1) * sizeof(int));
  size_t o_cur = alloc((size_t)N * sizeof(int));
  size_t o_srt = alloc((size_t)ET * sizeof(int));
  size_t o_ts = alloc((((size_t)N + 255) / 256) * sizeof(int));
  size_t base_sz = off;
  size_t o_agg = alloc((size_t)N * 256 * sizeof(float));  // 51.2 MB
  bool split = (ws_size >= off);
  (void)base_sz;

  float* wsrc = (float*)(ws + o_wsrc);
  float* wdst = (float*)(ws + o_wdst);
  float4* asrc4 = (float4*)(ws + o_asrc);
  float4* adst4 = (float4*)(ws + o_adst);
  int* cnt = (int*)(ws + o_cnt);
  int* row = (int*)(ws + o_row);
  int* cur = (int*)(ws + o_cur);
  int* srt = (int*)(ws + o_srt);
  int* tsum = (int*)(ws + o_ts);
  float* aggp = (float*)(ws + o_agg);

  hipMemsetAsync(cnt, 0, (size_t)N * sizeof(int), stream);

  patt_kernel<<<1, 256, 0, stream>>>(W, att_src, att_dst, wsrc, wdst);
  nattn_kernel<<<(N + 3) / 4, 256, 0, stream>>>(meta_x, (const float4*)wsrc,
                                                (const float4*)wdst, asrc4, adst4, N);
  if ((E & 3) == 0) {
    int nt4 = (E >> 2) + N;
    hist4_kernel<<<(nt4 + 255) / 256, 256, 0, stream>>>(ei, cnt, E, N);
  } else {
    hist_kernel<<<(ET + 255) / 256, 256, 0, stream>>>(ei, cnt, E, N);
  }
  int ntiles = (N + 255) / 256;
  scanA_kernel<<<ntiles, 256, 0, stream>>>(cnt, tsum, N);
  scanB_kernel<<<1, 256, 0, stream>>>(tsum, ntiles);
  scanC_kernel<<<ntiles, 256, 0, stream>>>(cnt, tsum, row, cur, N);
  if ((E & 3) == 0) {
    scatter8_kernel<<<2048, 256, 0, stream>>>(ei, cur, srt, E, N);
  } else {
    scatter_kernel<<<(ET + 255) / 256, 256, 0, stream>>>(ei, cur, srt, E, N);
  }
  if (split) {
    agg_kernel<<<(N + 3) / 4, 256, 0, stream>>>(srt, row, asrc4, adst4, meta_x, aggp, N);
    int ngroups = (N + 3) / 4;
    int pgrid = ngroups < 2048 ? ngroups : 2048;
    proj_kernel<<<pgrid, 256, 0, stream>>>(aggp, W, bias, out, N);
  } else {
    int ngroups = (N + 3) / 4;
    int ggrid = ngroups < 2048 ? ngroups : 2048;
    gatout_kernel<<<ggrid, 256, 0, stream>>>(srt, row, asrc4, adst4, meta_x, W, bias, out, N);
  }
}

// Round 10
// 192.722 us; speedup vs baseline: 2.2746x; 1.0227x over previous
//
#include <hip/hip_runtime.h>
#include <hip/hip_bf16.h>
#include <math.h>

#define MAXDEG 64

__device__ __forceinline__ float lrelu(float v) { return v > 0.0f ? v : 0.2f * v; }

// ---- Kernel A: fold attention vectors into W: wsrc[k,h] = sum_c W[k,h*64+c]*att_src[h,c]
__global__ void patt_kernel(const float* __restrict__ W, const float* __restrict__ att_src,
                            const float* __restrict__ att_dst, float* __restrict__ wsrc,
                            float* __restrict__ wdst) {
  int t = threadIdx.x;  // 256 threads: h = t>>6, k = t&63
  int h = t >> 6, k = t & 63;
  const float* wrow = W + (size_t)k * 256 + h * 64;
  const float* as = att_src + h * 64;
  const float* ad = att_dst + h * 64;
  float ss = 0.f, sd = 0.f;
#pragma unroll
  for (int c = 0; c < 64; ++c) {
    float w = wrow[c];
    ss = fmaf(w, as[c], ss);
    sd = fmaf(w, ad[c], sd);
  }
  wsrc[k * 4 + h] = ss;
  wdst[k * 4 + h] = sd;
}

// ---- Kernel B: per-node attention scalars + bf16 copy of x (side product).
__global__ void nattn_kernel(const float* __restrict__ x, const float4* __restrict__ wsrc4,
                             const float4* __restrict__ wdst4, float4* __restrict__ asrc4,
                             float4* __restrict__ adst4, __hip_bfloat16* __restrict__ xh,
                             int N) {
  int lane = threadIdx.x & 63;
  int n = blockIdx.x * 4 + (threadIdx.x >> 6);
  if (n >= N) return;
  float xv = x[(size_t)n * 64 + lane];
  xh[(size_t)n * 64 + lane] = __float2bfloat16(xv);
  float4 ws = wsrc4[lane], wd = wdst4[lane];
  float s0 = xv * ws.x, s1 = xv * ws.y, s2 = xv * ws.z, s3 = xv * ws.w;
  float d0 = xv * wd.x, d1 = xv * wd.y, d2 = xv * wd.z, d3 = xv * wd.w;
#pragma unroll
  for (int m = 1; m < 64; m <<= 1) {
    s0 += __shfl_xor(s0, m, 64); s1 += __shfl_xor(s1, m, 64);
    s2 += __shfl_xor(s2, m, 64); s3 += __shfl_xor(s3, m, 64);
    d0 += __shfl_xor(d0, m, 64); d1 += __shfl_xor(d1, m, 64);
    d2 += __shfl_xor(d2, m, 64); d3 += __shfl_xor(d3, m, 64);
  }
  if (lane == 0) {
    asrc4[n] = make_float4(s0, s1, s2, s3);
    adst4[n] = make_float4(d0, d1, d2, d3);
  }
}

// ---- Scalar hist/scatter [round-2 proven, fallback when E%4 != 0]
__global__ void hist_kernel(const int* __restrict__ ei, int* __restrict__ counts,
                            int E, int N) {
  int e = blockIdx.x * 256 + threadIdx.x;
  int ET = E + N;
  if (e >= ET) return;
  int dst = (e < E) ? ei[(size_t)E + e] : (e - E);
  atomicAdd(&counts[dst], 1);
}

__global__ void scatter_kernel(const int* __restrict__ ei, int* __restrict__ cursor,
                               int* __restrict__ src_sorted, int E, int N) {
  int e = blockIdx.x * 256 + threadIdx.x;
  int ET = E + N;
  if (e >= ET) return;
  int src, dst;
  if (e < E) {
    src = ei[e];
    dst = ei[(size_t)E + e];
  } else {
    src = dst = e - E;
  }
  int pos = atomicAdd(&cursor[dst], 1);
  src_sorted[pos] = src;
}

// ---- int4 hist (E%4==0 path) [proven r8]
__global__ void hist4_kernel(const int* __restrict__ ei, int* __restrict__ counts,
                             int E, int N) {
  int i = blockIdx.x * 256 + threadIdx.x;
  int E4 = E >> 2;
  if (i < E4) {
    int4 d = ((const int4*)(ei + E))[i];
    atomicAdd(&counts[d.x], 1);
    atomicAdd(&counts[d.y], 1);
    atomicAdd(&counts[d.z], 1);
    atomicAdd(&counts[d.w], 1);
  } else if (i < E4 + N) {
    atomicAdd(&counts[i - E4], 1);
  }
}

// ---- XCD-sliced scatter [proven r9]
__global__ void scatter8_kernel(const int* __restrict__ ei, int* __restrict__ cursor,
                                int* __restrict__ srt, int E, int N) {
  int slice = blockIdx.x & 7;
  int bid = blockIdx.x >> 3;
  int nb = gridDim.x >> 3;
  int chunk = (N + 7) >> 3;
  int lo = slice * chunk;
  int hi = lo + chunk; if (hi > N) hi = N;
  int E4 = E >> 2;
  const int4* s4p = (const int4*)ei;
  const int4* d4p = (const int4*)(ei + E);
  int stride = nb * 256;
  for (int i = bid * 256 + threadIdx.x; i < E4; i += stride) {
    int4 d4 = d4p[i];
    bool bx = (d4.x >= lo && d4.x < hi), by = (d4.y >= lo && d4.y < hi);
    bool bz = (d4.z >= lo && d4.z < hi), bw = (d4.w >= lo && d4.w < hi);
    if (!(bx || by || bz || bw)) continue;
    int4 s4 = s4p[i];
    if (bx) { int p = atomicAdd(&cursor[d4.x], 1); srt[p] = s4.x; }
    if (by) { int p = atomicAdd(&cursor[d4.y], 1); srt[p] = s4.y; }
    if (bz) { int p = atomicAdd(&cursor[d4.z], 1); srt[p] = s4.z; }
    if (bw) { int p = atomicAdd(&cursor[d4.w], 1); srt[p] = s4.w; }
  }
  for (int n = lo + bid * 256 + threadIdx.x; n < hi; n += stride) {
    int p = atomicAdd(&cursor[n], 1);
    srt[p] = n;
  }
}

// ---- Hierarchical scan [proven r5]
__global__ void scanA_kernel(const int* __restrict__ cnt, int* __restrict__ tsum, int N) {
  int b = blockIdx.x, t = threadIdx.x;
  int idx = b * 256 + t;
  int v = (idx < N) ? cnt[idx] : 0;
#pragma unroll
  for (int m = 1; m < 64; m <<= 1) v += __shfl_xor(v, m, 64);
  __shared__ int ws[4];
  if ((t & 63) == 0) ws[t >> 6] = v;
  __syncthreads();
  if (t == 0) tsum[b] = ws[0] + ws[1] + ws[2] + ws[3];
}

__global__ void scanB_kernel(int* __restrict__ tsum, int ntiles) {
  __shared__ int part[256];
  int t = threadIdx.x;
  int carry = 0;
  for (int b0 = 0; b0 < ntiles; b0 += 256) {
    int idx = b0 + t;
    int v = (idx < ntiles) ? tsum[idx] : 0;
    part[t] = v;
    __syncthreads();
    for (int d = 1; d < 256; d <<= 1) {
      int u = (t >= d) ? part[t - d] : 0;
      __syncthreads();
      part[t] += u;
      __syncthreads();
    }
    if (idx < ntiles) tsum[idx] = part[t] - v + carry;  // exclusive + carry
    carry += part[255];
    __syncthreads();
  }
}

__global__ void scanC_kernel(const int* __restrict__ cnt, const int* __restrict__ tsum,
                             int* __restrict__ row, int* __restrict__ cur, int N) {
  __shared__ int part[256];
  int b = blockIdx.x, t = threadIdx.x;
  int idx = b * 256 + t;
  int c = (idx < N) ? cnt[idx] : 0;
  part[t] = c;
  __syncthreads();
  for (int d = 1; d < 256; d <<= 1) {
    int u = (t >= d) ? part[t - d] : 0;
    __syncthreads();
    part[t] += u;
    __syncthreads();
  }
  int exc = part[t] - c + tsum[b];
  if (idx < N) {
    row[idx] = exc;
    cur[idx] = exc;
    if (idx == N - 1) row[N] = exc + c;
  }
}

// ---- Aggregation: one wave per node, zero barriers; x gathered as bf16 (half lines).
__global__ __launch_bounds__(256) void agg_kernel(
    const int* __restrict__ srt, const int* __restrict__ row,
    const float4* __restrict__ asrc4, const float4* __restrict__ adst4,
    const __hip_bfloat16* __restrict__ xh, float* __restrict__ agg, int N) {
  __shared__ float4 alL[4][MAXDEG];  // 4096B
  __shared__ int slL[4][MAXDEG];     // 1024B
  int t = threadIdx.x, w = t >> 6, lane = t & 63;
  int n = blockIdx.x * 4 + w;
  if (n >= N) return;
  int start = row[n], end = row[n + 1];
  int deg = end - start;
  float4 ad = adst4[n];
  float t0 = 0.f, t1 = 0.f, t2 = 0.f, t3 = 0.f;
  if (deg <= MAXDEG) {
    for (int b = 0; b < deg; b += 64) {
      if (b + lane < deg) {
        int sl = srt[start + b + lane];
        float4 as = asrc4[sl];
        float4 e;
        e.x = __expf(lrelu(as.x + ad.x));
        e.y = __expf(lrelu(as.y + ad.y));
        e.z = __expf(lrelu(as.z + ad.z));
        e.w = __expf(lrelu(as.w + ad.w));
        alL[w][b + lane] = e;
        slL[w][b + lane] = sl;
        t0 += e.x; t1 += e.y; t2 += e.z; t3 += e.w;
      }
    }
  } else {
    for (int b = start; b < end; b += 64) {
      int idx = b + lane;
      if (idx < end) {
        int sl = srt[idx];
        float4 as = asrc4[sl];
        t0 += __expf(lrelu(as.x + ad.x));
        t1 += __expf(lrelu(as.y + ad.y));
        t2 += __expf(lrelu(as.z + ad.z));
        t3 += __expf(lrelu(as.w + ad.w));
      }
    }
  }
#pragma unroll
  for (int m = 1; m < 64; m <<= 1) {
    t0 += __shfl_xor(t0, m, 64);
    t1 += __shfl_xor(t1, m, 64);
    t2 += __shfl_xor(t2, m, 64);
    t3 += __shfl_xor(t3, m, 64);
  }
  float r0 = 0.25f / (t0 + 1e-16f), r1 = 0.25f / (t1 + 1e-16f);
  float r2 = 0.25f / (t2 + 1e-16f), r3 = 0.25f / (t3 + 1e-16f);
  float a0 = 0.f, a1 = 0.f, a2 = 0.f, a3 = 0.f;
  if (deg <= MAXDEG) {
    int j = 0;
    for (; j + 4 <= deg; j += 4) {
      float4 e0 = alL[w][j], e1 = alL[w][j + 1], e2 = alL[w][j + 2], e3 = alL[w][j + 3];
      int q0 = slL[w][j], q1 = slL[w][j + 1], q2 = slL[w][j + 2], q3 = slL[w][j + 3];
      float v0 = __bfloat162float(xh[(size_t)q0 * 64 + lane]);
      float v1 = __bfloat162float(xh[(size_t)q1 * 64 + lane]);
      float v2 = __bfloat162float(xh[(size_t)q2 * 64 + lane]);
      float v3 = __bfloat162float(xh[(size_t)q3 * 64 + lane]);
      a0 = fmaf(e0.x, v0, a0); a1 = fmaf(e0.y, v0, a1);
      a2 = fmaf(e0.z, v0, a2); a3 = fmaf(e0.w, v0, a3);
      a0 = fmaf(e1.x, v1, a0); a1 = fmaf(e1.y, v1, a1);
      a2 = fmaf(e1.z, v1, a2); a3 = fmaf(e1.w, v1, a3);
      a0 = fmaf(e2.x, v2, a0); a1 = fmaf(e2.y, v2, a1);
      a2 = fmaf(e2.z, v2, a2); a3 = fmaf(e2.w, v2, a3);
      a0 = fmaf(e3.x, v3, a0); a1 = fmaf(e3.y, v3, a1);
      a2 = fmaf(e3.z, v3, a2); a3 = fmaf(e3.w, v3, a3);
    }
    for (; j < deg; ++j) {
      float4 e0 = alL[w][j];
      int q0 = slL[w][j];
      float v0 = __bfloat162float(xh[(size_t)q0 * 64 + lane]);
      a0 = fmaf(e0.x, v0, a0); a1 = fmaf(e0.y, v0, a1);
      a2 = fmaf(e0.z, v0, a2); a3 = fmaf(e0.w, v0, a3);
    }
  } else {
    for (int b = start; b < end; b += 64) {
      int cnt = end - b;
      if (cnt > 64) cnt = 64;
      int idx = b + lane;
      int sl = 0;
      float e0 = 0.f, e1 = 0.f, e2 = 0.f, e3 = 0.f;
      if (idx < end) {
        sl = srt[idx];
        float4 as = asrc4[sl];
        e0 = __expf(lrelu(as.x + ad.x));
        e1 = __expf(lrelu(as.y + ad.y));
        e2 = __expf(lrelu(as.z + ad.z));
        e3 = __expf(lrelu(as.w + ad.w));
      }
      for (int j = 0; j < cnt; ++j) {
        int sj = __shfl(sl, j, 64);
        float b0 = __shfl(e0, j, 64), b1 = __shfl(e1, j, 64);
        float b2 = __shfl(e2, j, 64), b3 = __shfl(e3, j, 64);
        float v = __bfloat162float(xh[(size_t)sj * 64 + lane]);
        a0 = fmaf(b0, v, a0); a1 = fmaf(b1, v, a1);
        a2 = fmaf(b2, v, a2); a3 = fmaf(b3, v, a3);
      }
    }
  }
  float* ao = agg + (size_t)n * 256;
  ao[lane] = a0 * r0;
  ao[64 + lane] = a1 * r1;
  ao[128 + lane] = a2 * r2;
  ao[192 + lane] = a3 * r3;
}

// ---- Projection [proven r8]
__global__ __launch_bounds__(256) void proj_kernel(
    const float* __restrict__ agg, const float* __restrict__ W,
    const float* __restrict__ bias, float* __restrict__ out, int N) {
  __shared__ float aggL[4][256];   // 4KB
  __shared__ float pL[4][4][64];   // 4KB
  int t = threadIdx.x, w = t >> 6, lane = t & 63;
  float Wreg[64];  // W[k, w*64 + lane]
#pragma unroll
  for (int k = 0; k < 64; ++k) Wreg[k] = W[(size_t)k * 256 + w * 64 + lane];
  float bv = bias[lane];
  int ngroups = (N + 3) >> 2;
  for (int g = blockIdx.x; g < ngroups; g += gridDim.x) {
    int n0 = g * 4;
    __syncthreads();
    {
      int nn = n0 + w;
      if (nn < N)
        *(float4*)&aggL[w][(t & 63) * 4] =
            *(const float4*)&agg[(size_t)nn * 256 + (t & 63) * 4];
      else
        *(float4*)&aggL[w][(t & 63) * 4] = make_float4(0.f, 0.f, 0.f, 0.f);
    }
    __syncthreads();
    float acc0 = 0.f, acc1 = 0.f, acc2 = 0.f, acc3 = 0.f;
#pragma unroll
    for (int k4 = 0; k4 < 16; ++k4) {
      float4 av0 = *(const float4*)&aggL[0][w * 64 + k4 * 4];
      float4 av1 = *(const float4*)&aggL[1][w * 64 + k4 * 4];
      float4 av2 = *(const float4*)&aggL[2][w * 64 + k4 * 4];
      float4 av3 = *(const float4*)&aggL[3][w * 64 + k4 * 4];
      float w0 = Wreg[k4 * 4 + 0], w1 = Wreg[k4 * 4 + 1];
      float w2 = Wreg[k4 * 4 + 2], w3 = Wreg[k4 * 4 + 3];
      acc0 = fmaf(av0.x, w0, acc0); acc0 = fmaf(av0.y, w1, acc0);
      acc0 = fmaf(av0.z, w2, acc0); acc0 = fmaf(av0.w, w3, acc0);
      acc1 = fmaf(av1.x, w0, acc1); acc1 = fmaf(av1.y, w1, acc1);
      acc1 = fmaf(av1.z, w2, acc1); acc1 = fmaf(av1.w, w3, acc1);
      acc2 = fmaf(av2.x, w0, acc2); acc2 = fmaf(av2.y, w1, acc2);
      acc2 = fmaf(av2.z, w2, acc2); acc2 = fmaf(av2.w, w3, acc2);
      acc3 = fmaf(av3.x, w0, acc3); acc3 = fmaf(av3.y, w1, acc3);
      acc3 = fmaf(av3.z, w2, acc3); acc3 = fmaf(av3.w, w3, acc3);
    }
    pL[w][0][lane] = acc0;
    pL[w][1][lane] = acc1;
    pL[w][2][lane] = acc2;
    pL[w][3][lane] = acc3;
    __syncthreads();
    int nn = n0 + w;
    if (nn < N) {
      out[(size_t)nn * 64 + lane] = pL[0][w][lane] + pL[1][w][lane] +
                                    pL[2][w][lane] + pL[3][w][lane] + bv;
    }
  }
}

// ---- Fused fallback (r6-proven, f32 x) used only if ws_size is too small.
__global__ __launch_bounds__(256) void gatout_kernel(
    const int* __restrict__ srt, const int* __restrict__ row,
    const float4* __restrict__ asrc4, const float4* __restrict__ adst4,
    const float* __restrict__ x, const float* __restrict__ W,
    const float* __restrict__ bias, float* __restrict__ out, int N) {
  __shared__ float4 smem4[320];
  float4 (*alL)[MAXDEG] = (float4(*)[MAXDEG])smem4;
  int (*slL)[MAXDEG] = (int(*)[MAXDEG])(smem4 + 256);
  float (*buf)[4][64] = (float(*)[4][64])smem4;
  int t = threadIdx.x, w = t >> 6, lane = t & 63;
  float Wreg[64];
#pragma unroll
  for (int k = 0; k < 64; ++k) Wreg[k] = W[(size_t)k * 256 + w * 64 + lane];
  float bv = bias[lane];
  int ngroups = (N + 3) >> 2;
  for (int g = blockIdx.x; g < ngroups; g += gridDim.x) {
    int n = g * 4 + w;
    float a0 = 0.f, a1 = 0.f, a2 = 0.f, a3 = 0.f;
    float r0 = 0.f, r1 = 0.f, r2 = 0.f, r3 = 0.f;
    __syncthreads();
    if (n < N) {
      int start = row[n], end = row[n + 1];
      int deg = end - start;
      float4 ad = adst4[n];
      float t0 = 0.f, t1 = 0.f, t2 = 0.f, t3 = 0.f;
      if (deg <= MAXDEG) {
        for (int b = 0; b < deg; b += 64) {
          if (b + lane < deg) {
            int sl = srt[start + b + lane];
            float4 as = asrc4[sl];
            float4 e;
            e.x = __expf(lrelu(as.x + ad.x));
            e.y = __expf(lrelu(as.y + ad.y));
            e.z = __expf(lrelu(as.z + ad.z));
            e.w = __expf(lrelu(as.w + ad.w));
            alL[w][b + lane] = e;
            slL[w][b + lane] = sl;
            t0 += e.x; t1 += e.y; t2 += e.z; t3 += e.w;
          }
        }
      } else {
        for (int b = start; b < end; b += 64) {
          int idx = b + lane;
          if (idx < end) {
            int sl = srt[idx];
            float4 as = asrc4[sl];
            t0 += __expf(lrelu(as.x + ad.x));
            t1 += __expf(lrelu(as.y + ad.y));
            t2 += __expf(lrelu(as.z + ad.z));
            t3 += __expf(lrelu(as.w + ad.w));
          }
        }
      }
#pragma unroll
      for (int m = 1; m < 64; m <<= 1) {
        t0 += __shfl_xor(t0, m, 64);
        t1 += __shfl_xor(t1, m, 64);
        t2 += __shfl_xor(t2, m, 64);
        t3 += __shfl_xor(t3, m, 64);
      }
      r0 = 0.25f / (t0 + 1e-16f); r1 = 0.25f / (t1 + 1e-16f);
      r2 = 0.25f / (t2 + 1e-16f); r3 = 0.25f / (t3 + 1e-16f);
      if (deg <= MAXDEG) {
        int j = 0;
        for (; j + 4 <= deg; j += 4) {
          float4 e0 = alL[w][j], e1 = alL[w][j + 1], e2 = alL[w][j + 2], e3 = alL[w][j + 3];
          int q0 = slL[w][j], q1 = slL[w][j + 1], q2 = slL[w][j + 2], q3 = slL[w][j + 3];
          float v0 = x[(size_t)q0 * 64 + lane];
          float v1 = x[(size_t)q1 * 64 + lane];
          float v2 = x[(size_t)q2 * 64 + lane];
          float v3 = x[(size_t)q3 * 64 + lane];
          a0 = fmaf(e0.x, v0, a0); a1 = fmaf(e0.y, v0, a1);
          a2 = fmaf(e0.z, v0, a2); a3 = fmaf(e0.w, v0, a3);
          a0 = fmaf(e1.x, v1, a0); a1 = fmaf(e1.y, v1, a1);
          a2 = fmaf(e1.z, v1, a2); a3 = fmaf(e1.w, v1, a3);
          a0 = fmaf(e2.x, v2, a0); a1 = fmaf(e2.y, v2, a1);
          a2 = fmaf(e2.z, v2, a2); a3 = fmaf(e2.w, v2, a3);
          a0 = fmaf(e3.x, v3, a0); a1 = fmaf(e3.y, v3, a1);
          a2 = fmaf(e3.z, v3, a2); a3 = fmaf(e3.w, v3, a3);
        }
        for (; j < deg; ++j) {
          float4 e0 = alL[w][j];
          int q0 = slL[w][j];
          float v0 = x[(size_t)q0 * 64 + lane];
          a0 = fmaf(e0.x, v0, a0); a1 = fmaf(e0.y, v0, a1);
          a2 = fmaf(e0.z, v0, a2); a3 = fmaf(e0.w, v0, a3);
        }
      } else {
        for (int b = start; b < end; b += 64) {
          int cnt = end - b;
          if (cnt > 64) cnt = 64;
          int idx = b + lane;
          int sl = 0;
          float e0 = 0.f, e1 = 0.f, e2 = 0.f, e3 = 0.f;
          if (idx < end) {
            sl = srt[idx];
            float4 as = asrc4[sl];
            e0 = __expf(lrelu(as.x + ad.x));
            e1 = __expf(lrelu(as.y + ad.y));
            e2 = __expf(lrelu(as.z + ad.z));
            e3 = __expf(lrelu(as.w + ad.w));
          }
          for (int j = 0; j < cnt; ++j) {
            int sj = __shfl(sl, j, 64);
            float b0 = __shfl(e0, j, 64), b1 = __shfl(e1, j, 64);
            float b2 = __shfl(e2, j, 64), b3 = __shfl(e3, j, 64);
            float v = x[(size_t)sj * 64 + lane];
            a0 = fmaf(b0, v, a0); a1 = fmaf(b1, v, a1);
            a2 = fmaf(b2, v, a2); a3 = fmaf(b3, v, a3);
          }
        }
      }
    }
    __syncthreads();
    buf[w][0][lane] = a0 * r0;
    buf[w][1][lane] = a1 * r1;
    buf[w][2][lane] = a2 * r2;
    buf[w][3][lane] = a3 * r3;
    __syncthreads();
    float acc0 = 0.f, acc1 = 0.f, acc2 = 0.f, acc3 = 0.f;
#pragma unroll
    for (int k4 = 0; k4 < 16; ++k4) {
      float4 av0 = *(const float4*)&buf[0][w][k4 * 4];
      float4 av1 = *(const float4*)&buf[1][w][k4 * 4];
      float4 av2 = *(const float4*)&buf[2][w][k4 * 4];
      float4 av3 = *(const float4*)&buf[3][w][k4 * 4];
      float w0 = Wreg[k4 * 4 + 0], w1 = Wreg[k4 * 4 + 1];
      float w2 = Wreg[k4 * 4 + 2], w3 = Wreg[k4 * 4 + 3];
      acc0 = fmaf(av0.x, w0, acc0); acc0 = fmaf(av0.y, w1, acc0);
      acc0 = fmaf(av0.z, w2, acc0); acc0 = fmaf(av0.w, w3, acc0);
      acc1 = fmaf(av1.x, w0, acc1); acc1 = fmaf(av1.y, w1, acc1);
      acc1 = fmaf(av1.z, w2, acc1); acc1 = fmaf(av1.w, w3, acc1);
      acc2 = fmaf(av2.x, w0, acc2); acc2 = fmaf(av2.y, w1, acc2);
      acc2 = fmaf(av2.z, w2, acc2); acc2 = fmaf(av2.w, w3, acc2);
      acc3 = fmaf(av3.x, w0, acc3); acc3 = fmaf(av3.y, w1, acc3);
      acc3 = fmaf(av3.z, w2, acc3); acc3 = fmaf(av3.w, w3, acc3);
    }
    __syncthreads();
    buf[w][0][lane] = acc0;
    buf[w][1][lane] = acc1;
    buf[w][2][lane] = acc2;
    buf[w][3][lane] = acc3;
    __syncthreads();
    if (n < N) {
      out[(size_t)n * 64 + lane] = buf[0][w][lane] + buf[1][w][lane] +
                                   buf[2][w][lane] + buf[3][w][lane] + bv;
    }
  }
}

extern "C" void kernel_launch(void* const* d_in, const int* in_sizes, int n_in,
                              void* d_out, int out_size, void* d_ws, size_t ws_size,
                              hipStream_t stream) {
  const float* meta_x = (const float*)d_in[0];
  const int* ei = (const int*)d_in[1];  // int32 edge index [2,E] flat
  const float* W = (const float*)d_in[2];
  const float* att_src = (const float*)d_in[3];
  const float* att_dst = (const float*)d_in[4];
  const float* bias = (const float*)d_in[5];
  float* out = (float*)d_out;

  int N = in_sizes[0] / 64;
  int E = in_sizes[1] / 2;
  int ET = E + N;

  char* ws = (char*)d_ws;
  size_t off = 0;
  auto alloc = [&](size_t bytes) {
    size_t o = off;
    off += (bytes + 255) & ~(size_t)255;
    return o;
  };
  size_t o_wsrc = alloc(64 * 4 * sizeof(float));
  size_t o_wdst = alloc(64 * 4 * sizeof(float));
  size_t o_asrc = alloc((size_t)N * 4 * sizeof(float));
  size_t o_adst = alloc((size_t)N * 4 * sizeof(float));
  size_t o_cnt = alloc((size_t)N * sizeof(int));
  size_t o_row = alloc(((size_t)N + 1) * sizeof(int));
  size_t o_cur = alloc((size_t)N * sizeof(int));
  size_t o_srt = alloc((size_t)ET * sizeof(int));
  size_t o_ts = alloc((((size_t)N + 255) / 256) * sizeof(int));
  size_t o_xh = alloc((size_t)N * 64 * sizeof(__hip_bfloat16));  // 6.4 MB
  size_t o_agg = alloc((size_t)N * 256 * sizeof(float));         // 51.2 MB
  bool split = (ws_size >= off);

  float* wsrc = (float*)(ws + o_wsrc);
  float* wdst = (float*)(ws + o_wdst);
  float4* asrc4 = (float4*)(ws + o_asrc);
  float4* adst4 = (float4*)(ws + o_adst);
  int* cnt = (int*)(ws + o_cnt);
  int* row = (int*)(ws + o_row);
  int* cur = (int*)(ws + o_cur);
  int* srt = (int*)(ws + o_srt);
  int* tsum = (int*)(ws + o_ts);
  __hip_bfloat16* xh = (__hip_bfloat16*)(ws + o_xh);
  float* aggp = (float*)(ws + o_agg);

  hipMemsetAsync(cnt, 0, (size_t)N * sizeof(int), stream);

  patt_kernel<<<1, 256, 0, stream>>>(W, att_src, att_dst, wsrc, wdst);
  nattn_kernel<<<(N + 3) / 4, 256, 0, stream>>>(meta_x, (const float4*)wsrc,
                                                (const float4*)wdst, asrc4, adst4, xh, N);
  if ((E & 3) == 0) {
    int nt4 = (E >> 2) + N;
    hist4_kernel<<<(nt4 + 255) / 256, 256, 0, stream>>>(ei, cnt, E, N);
  } else {
    hist_kernel<<<(ET + 255) / 256, 256, 0, stream>>>(ei, cnt, E, N);
  }
  int ntiles = (N + 255) / 256;
  scanA_kernel<<<ntiles, 256, 0, stream>>>(cnt, tsum, N);
  scanB_kernel<<<1, 256, 0, stream>>>(tsum, ntiles);
  scanC_kernel<<<ntiles, 256, 0, stream>>>(cnt, tsum, row, cur, N);
  if ((E & 3) == 0) {
    scatter8_kernel<<<2048, 256, 0, stream>>>(ei, cur, srt, E, N);
  } else {
    scatter_kernel<<<(ET + 255) / 256, 256, 0, stream>>>(ei, cur, srt, E, N);
  }
  if (split) {
    agg_kernel<<<(N + 3) / 4, 256, 0, stream>>>(srt, row, asrc4, adst4, xh, aggp, N);
    int ngroups = (N + 3) / 4;
    int pgrid = ngroups < 2048 ? ngroups : 2048;
    proj_kernel<<<pgrid, 256, 0, stream>>>(aggp, W, bias, out, N);
  } else {
    int ngroups = (N + 3) / 4;
    int ggrid = ngroups < 2048 ? ngroups : 2048;
    gatout_kernel<<<ggrid, 256, 0, stream>>>(srt, row, asrc4, adst4, meta_x, W, bias, out, N);
  }
}